// Round 6
// baseline (318.433 us; speedup 1.0000x reference)
//
#include <hip/hip_runtime.h>

typedef __attribute__((ext_vector_type(8))) __bf16 bf16x8;
typedef __attribute__((ext_vector_type(16))) float f32x16;

__device__ __forceinline__ unsigned short f2bf(float f) {
    unsigned int u = __float_as_uint(f);
    unsigned int r = (u + 0x7FFFu + ((u >> 16) & 1u)) >> 16;
    return (unsigned short)r;
}

// async global->LDS, 16B per lane (m97 pattern)
#define GLL16(gp, lp) \
    __builtin_amdgcn_global_load_lds( \
        (const __attribute__((address_space(1))) unsigned int*)(gp), \
        (__attribute__((address_space(3))) unsigned int*)(lp), 16, 0, 0)

// ---------------------------------------------------------------------------
// prep_w1t: w1 [32oc][1][41kh][11kw] f32 -> w1t [kw][oc][kh pad 48] bf16.
// ---------------------------------------------------------------------------
__global__ __launch_bounds__(256) void prep_w1t(const float* __restrict__ w1,
                                                unsigned short* __restrict__ w1t)
{
    const int t = blockIdx.x * 256 + threadIdx.x;   // 66 blocks -> exactly 16896
    const int k    = t % 48;
    const int rest = t / 48;
    const int oc   = rest & 31;
    const int kw   = rest >> 5;
    unsigned short v = 0;
    if (k < 41) v = f2bf(w1[(oc * 41 + k) * 11 + kw]);
    w1t[t] = v;
}

// ---------------------------------------------------------------------------
// prep_w2f: w2 [32oc][32ic][21][11] f32 -> dense A-fragments for 32x32x16:
//   w2tf[khp 0..32][kw 0..10][s 0..1][lane 0..63][8 bf16],  kh = khp - 6
// (zero outside [0,20]; wide pad lets conv2's J=4 j-loop run branchless).
// element: oc = l&31, ic = s*16 + (l>>5)*8 + j.
// ---------------------------------------------------------------------------
__global__ __launch_bounds__(256) void prep_w2f(const float* __restrict__ w2,
                                                unsigned short* __restrict__ w2tf)
{
    const int gid = blockIdx.x * 256 + threadIdx.x;  // 2904 blocks -> 743424 exact
    const int j  = gid & 7;
    const int l  = (gid >> 3) & 63;
    const int s  = (gid >> 9) & 1;
    const int ti = gid >> 10;        // 0..362
    const int khp = ti / 11;
    const int kw  = ti - khp * 11;
    const int kh  = khp - 6;
    const int oc  = l & 31;
    const int ic  = s * 16 + ((l >> 5) << 3) + j;
    unsigned short v = 0;
    if ((unsigned)kh <= 20u)
        v = f2bf(w2[((oc * 32 + ic) * 21 + kh) * 11 + kw]);
    w2tf[gid] = v;
}

// ---------------------------------------------------------------------------
// zero_halo: zero halo cols (c<5, c>=517) of planar h1s for all (n,r,icq).
// h1s layout: [n][r 0..80][icq 0..3][c 0..527][16B]  (plane = 8448 B)
// ---------------------------------------------------------------------------
__global__ __launch_bounds__(256) void zero_halo(unsigned short* __restrict__ h1s)
{
    const int id  = blockIdx.x * 256 + threadIdx.x;  // 324 blocks -> 82944 exact
    const int c16 = id & 15;
    const int q   = (id >> 4) & 3;
    const int nr  = id >> 6;                         // 0..1295
    const int c   = c16 < 5 ? c16 : 512 + c16;       // 0..4, 517..527
    uint4 z = {0u, 0u, 0u, 0u};
    *(uint4*)((char*)h1s + ((size_t)(nr * 4 + q) * 528 + c) * 16) = z;
}

// ---------------------------------------------------------------------------
// conv1_mfma: conv1 (41x11, s(2,2), p(20,5)) + bias + bn1 + clip + mask,
// 11 kw-taps of M=32(oc) x K=48(kh zero-pad) x N=ow GEMM on mfma_32x32x16_bf16.
// Epilogue transposes through LDS into the planar h1s layout.
// grid (4 ow-tiles, 41 oh-groups, 16 n), block 256.  (unchanged, verified)
// ---------------------------------------------------------------------------
__global__ __launch_bounds__(256) void conv1_mfma(
    const float* __restrict__ x, const int* __restrict__ xlen,
    const unsigned short* __restrict__ w1t,
    const float* __restrict__ b1, const float* __restrict__ g1,
    const float* __restrict__ be1, const float* __restrict__ m1,
    const float* __restrict__ v1,
    unsigned short* __restrict__ h1s)
{
    __shared__ uint4 lds4[2128];            // 34048 B: x-tile, then transpose buf
    char* lds = (char*)lds4;

    const int t  = threadIdx.x;
    const int bx = blockIdx.x;
    const int yi = blockIdx.y;
    const int n  = blockIdx.z;
    const int oh0 = ((yi >> 2) << 3) + (yi & 3);   // covers oh 0..80 with +4 pair
    const int len = xlen[n];

    const int l   = t & 63;
    const int w   = t >> 6;
    const int l31 = l & 31;
    const int lhi = l >> 5;

    char* h8 = (char*)h1s;
    const size_t rowpitch = 33792;          // 4 planes x 528 x 16B

    // dead strip: all cols masked -> store zeros, skip everything
    if (bx * 128 >= len) {
        #pragma unroll
        for (int it = 0; it < 4; ++it) {
            const int idx = t + it * 256;
            const int d1 = idx >> 9;
            const int q  = (idx >> 7) & 3;
            const int cl = idx & 127;
            const int oh = oh0 + 4 * d1;
            if (oh <= 80) {
                uint4 z = {0u, 0u, 0u, 0u};
                *(uint4*)(h8 + (size_t)(n * 81 + oh) * rowpitch + q * 8448
                          + (5 + (bx << 7) + cl) * 16) = z;
            }
        }
        return;
    }

    // ---- stage x: f32 -> bf16, transposed, swizzled ----
    const int cw   = t & 63;
    const int jrow = t >> 6;
    const int gr0  = 2 * oh0 - 20;
    const int gc0  = bx * 256 - 5;
    const float* xn = x + (size_t)n * 161 * 1024;
    #pragma unroll
    for (int cg = 0; cg < 5; ++cg) {
        const int c = cg * 64 + cw;
        if (c < 266) {
            const int gc = gc0 + c;
            const bool cok = (gc >= 0) && (gc < 1024);
            #pragma unroll
            for (int jj = 0; jj < 2; ++jj) {
                const int j = jrow + 4 * jj;       // chunk 0..6
                if (j < 7) {
                    unsigned int u[4];
                    #pragma unroll
                    for (int q = 0; q < 4; ++q) {
                        const int rA = gr0 + 8 * j + 2 * q;
                        float lo = 0.f, hi = 0.f;
                        if (cok && rA >= 0 && rA < 161)         lo = xn[(size_t)rA * 1024 + gc];
                        if (cok && rA + 1 >= 0 && rA + 1 < 161) hi = xn[(size_t)(rA + 1) * 1024 + gc];
                        u[q] = (unsigned int)f2bf(lo) | ((unsigned int)f2bf(hi) << 16);
                    }
                    uint4 val; val.x = u[0]; val.y = u[1]; val.z = u[2]; val.w = u[3];
                    *(uint4*)(lds + c * 128 + ((j ^ ((c >> 1) & 7)) << 4)) = val;
                }
            }
        }
    }
    __syncthreads();

    // ---- compute ----
    const int i = (w << 5) + l31;        // 0..127: ow within tile

    f32x16 acc0 = {}, acc1 = {};
    const char* w1tb = (const char*)w1t;
    #pragma unroll
    for (int kw = 0; kw < 11; ++kw) {
        const char* ap = w1tb + kw * 3072 + l31 * 96 + lhi * 16;
        const bf16x8 a0 = *(const bf16x8*)(ap);
        const bf16x8 a1 = *(const bf16x8*)(ap + 32);
        const bf16x8 a2 = *(const bf16x8*)(ap + 64);
        const int c = 2 * i + kw;
        const char* cb = lds + c * 128;
        const int sw = (c >> 1) & 7;
        const bf16x8 b00 = *(const bf16x8*)(cb + (((0 + lhi) ^ sw) << 4));
        const bf16x8 b01 = *(const bf16x8*)(cb + (((2 + lhi) ^ sw) << 4));
        const bf16x8 b02 = *(const bf16x8*)(cb + (((4 + lhi) ^ sw) << 4));
        const bf16x8 b10 = *(const bf16x8*)(cb + (((1 + lhi) ^ sw) << 4));
        const bf16x8 b11 = *(const bf16x8*)(cb + (((3 + lhi) ^ sw) << 4));
        const bf16x8 b12 = *(const bf16x8*)(cb + (((5 + lhi) ^ sw) << 4));
        acc0 = __builtin_amdgcn_mfma_f32_32x32x16_bf16(a0, b00, acc0, 0, 0, 0);
        acc0 = __builtin_amdgcn_mfma_f32_32x32x16_bf16(a1, b01, acc0, 0, 0, 0);
        acc0 = __builtin_amdgcn_mfma_f32_32x32x16_bf16(a2, b02, acc0, 0, 0, 0);
        acc1 = __builtin_amdgcn_mfma_f32_32x32x16_bf16(a0, b10, acc1, 0, 0, 0);
        acc1 = __builtin_amdgcn_mfma_f32_32x32x16_bf16(a1, b11, acc1, 0, 0, 0);
        acc1 = __builtin_amdgcn_mfma_f32_32x32x16_bf16(a2, b12, acc1, 0, 0, 0);
    }

    // ---- epilogue: bn1+clip+mask -> LDS transpose (planar) -> h1s ----
    __syncthreads();                     // x-tile reads done; reuse LDS
    const int ow  = bx * 128 + i;
    const bool vmask = ow < len;
    #pragma unroll
    for (int d1 = 0; d1 < 2; ++d1) {
        const int oh = oh0 + 4 * d1;
        if (oh <= 80) {
            #pragma unroll
            for (int q = 0; q < 4; ++q) {   // q = icq plane (oc>>3)
                float vv[4];
                #pragma unroll
                for (int rr = 0; rr < 4; ++rr) {
                    const int reg = (q << 2) + rr;
                    const int oc  = rr + (q << 3) + (lhi << 2);
                    const float s = g1[oc] * rsqrtf(v1[oc] + 1e-5f);
                    float val = ((d1 ? acc1[reg] : acc0[reg]) + b1[oc] - m1[oc]) * s + be1[oc];
                    val = fminf(fmaxf(val, 0.f), 20.f);
                    vv[rr] = vmask ? val : 0.f;
                }
                uint2 pk;
                pk.x = (unsigned int)f2bf(vv[0]) | ((unsigned int)f2bf(vv[1]) << 16);
                pk.y = (unsigned int)f2bf(vv[2]) | ((unsigned int)f2bf(vv[3]) << 16);
                *(uint2*)(lds + (((d1 << 2) + q) << 11) + i * 16 + lhi * 8) = pk;
            }
        }
    }
    __syncthreads();
    #pragma unroll
    for (int it = 0; it < 4; ++it) {
        const int idx = t + it * 256;    // 0..1023
        const int d1 = idx >> 9;
        const int q  = (idx >> 7) & 3;
        const int cl = idx & 127;
        const int oh = oh0 + 4 * d1;
        if (oh <= 80) {
            const uint4 v = *(const uint4*)(lds + (((d1 << 2) + q) << 11) + cl * 16);
            *(uint4*)(h8 + (size_t)(n * 81 + oh) * rowpitch + q * 8448
                      + (5 + (bx << 7) + cl) * 16) = v;
        }
    }
}

// ---------------------------------------------------------------------------
// conv2_v6: conv2 (32ic, 21x11, s(2,1), p(10,5)) + bias + bn2 + clip + mask.
// Block = 4 waves; tile = 256 cols (C=8) x 4 oh2 (J=4).  Wave owns 64
// DISTINCT cols (d_B=1) x all 4 j -> acc = 8 frags (128 VGPR); per (kw,s):
// 2 B ds_reads + 4 A loads (L1-dedup'd across waves) + 8 MFMA.
// A:MFMA = 1.14, LDS:MFMA ~1.2-1.5 -> ~60% structural ceiling.
// Grid 352, multiplicative scramble (x181 mod 352) for XCD/CU load balance.
// ---------------------------------------------------------------------------
__global__ __launch_bounds__(256, 2) void conv2_v6(
    const unsigned short* __restrict__ h1s, const unsigned short* __restrict__ w2tf,
    const int* __restrict__ xlen,
    const float* __restrict__ b2, const float* __restrict__ g2,
    const float* __restrict__ be2, const float* __restrict__ m2,
    const float* __restrict__ v2, float* __restrict__ out)
{
    __shared__ char lbuf[2][17408];      // 2 x (4 planes x 272 cols x 16B)

    const int t   = threadIdx.x;
    const int w   = t >> 6;
    const int l   = t & 63;
    const int l31 = l & 31;
    const int lhi = l >> 5;

    // scrambled bijective decode: lb = bid*181 mod 352 (gcd(181,352)=1)
    const int bid = blockIdx.x;
    const int lb  = (bid * 181) % 352;
    const int n   = lb / 22;
    const int rr  = lb - n * 22;
    const int by  = rr >> 1;             // 0..10: oh2 group {4by..4by+3}
    const int bx  = rr & 1;

    const int ow0 = bx << 8;
    const int len = xlen[n];

    if (ow0 >= len) {                    // fully masked col-tile: zeros only
        #pragma unroll
        for (int j = 0; j < 4; ++j) {
            const int oh2 = 4 * by + j;
            if (oh2 <= 40) {
                #pragma unroll
                for (int f = 0; f < 2; ++f) {
                    const int ow = ow0 + (w << 6) + (f << 5) + l31;
                    #pragma unroll
                    for (int reg = 0; reg < 16; ++reg) {
                        const int oc = (reg & 3) + ((reg >> 2) << 3) + (lhi << 2);
                        out[((size_t)(n * 32 + oc) * 41 + oh2) * 512 + ow] = 0.f;
                    }
                }
            }
        }
        return;
    }

    const int rlo = (8 * by - 10 > 0) ? 8 * by - 10 : 0;
    const int rhi = (8 * by + 16 < 80) ? 8 * by + 16 : 80;

    f32x16 acc[4][2] = {};               // [j][f]

    const char* nb = (const char*)h1s + (size_t)(n * 81) * 33792 + (size_t)(ow0 << 4);

    // stage: wave w DMAs plane w, 272 cols x 16B = 4352B (5 issues)
    #define STAGE(r, buf) do { \
        const char* g_ = nb + (size_t)(r) * 33792 + w * 8448; \
        char* d_ = &lbuf[buf][0] + w * 4352; \
        GLL16(g_ + l * 16,        d_ + l * 16); \
        GLL16(g_ + 1024 + l * 16, d_ + 1024 + l * 16); \
        GLL16(g_ + 2048 + l * 16, d_ + 2048 + l * 16); \
        GLL16(g_ + 3072 + l * 16, d_ + 3072 + l * 16); \
        if (l < 16) GLL16(g_ + 4096 + l * 16, d_ + 4096 + l * 16); \
    } while (0)

    STAGE(rlo, 0);
    __syncthreads();

    const char* w8v = (const char*)w2tf;
    int cur = 0;
    for (int r = rlo; r <= rhi; ++r) {
        if (r < rhi) STAGE(r + 1, cur ^ 1);
        const char* lb8 = &lbuf[cur][0];
        const int khb6 = r - 8 * by + 16;          // khp_j = khb6 - 2j in [0,32]
        #pragma unroll
        for (int kw = 0; kw < 11; ++kw) {
            const int cb = (w << 6) + kw + l31;
            #pragma unroll
            for (int s = 0; s < 2; ++s) {
                const char* bp = lb8 + (2 * s + lhi) * 4352 + cb * 16;
                const bf16x8 B0 = *(const bf16x8*)(bp);
                const bf16x8 B1 = *(const bf16x8*)(bp + 512);
                #pragma unroll
                for (int j = 0; j < 4; ++j) {
                    const int khp = khb6 - 2 * j;
                    const bf16x8 A = *(const bf16x8*)(w8v
                        + (size_t)(((khp * 11 + kw) * 2 + s) << 10) + (l << 4));
                    acc[j][0] = __builtin_amdgcn_mfma_f32_32x32x16_bf16(A, B0, acc[j][0], 0, 0, 0);
                    acc[j][1] = __builtin_amdgcn_mfma_f32_32x32x16_bf16(A, B1, acc[j][1], 0, 0, 0);
                }
            }
        }
        __syncthreads();
        cur ^= 1;
    }
    #undef STAGE

    // ---- epilogue: bias + bn2 + clip + mask -> out ----
    #pragma unroll
    for (int j = 0; j < 4; ++j) {
        const int oh2 = 4 * by + j;
        if (oh2 <= 40) {
            #pragma unroll
            for (int f = 0; f < 2; ++f) {
                const int ow = ow0 + (w << 6) + (f << 5) + l31;
                const bool valid = ow < len;
                #pragma unroll
                for (int reg = 0; reg < 16; ++reg) {
                    const int oc = (reg & 3) + ((reg >> 2) << 3) + (lhi << 2);
                    const float sc = g2[oc] * rsqrtf(v2[oc] + 1e-5f);
                    float val = (acc[j][f][reg] + b2[oc] - m2[oc]) * sc + be2[oc];
                    val = fminf(fmaxf(val, 0.f), 20.f);
                    if (!valid) val = 0.f;
                    out[((size_t)(n * 32 + oc) * 41 + oh2) * 512 + ow] = val;
                }
            }
        }
    }
}

extern "C" void kernel_launch(void* const* d_in, const int* in_sizes, int n_in,
                              void* d_out, int out_size, void* d_ws, size_t ws_size,
                              hipStream_t stream) {
    const float* x    = (const float*)d_in[0];
    const int*   xlen = (const int*)  d_in[1];
    const float* w1   = (const float*)d_in[2];
    const float* b1   = (const float*)d_in[3];
    const float* g1   = (const float*)d_in[4];
    const float* be1  = (const float*)d_in[5];
    const float* m1   = (const float*)d_in[6];
    const float* v1   = (const float*)d_in[7];
    const float* w2   = (const float*)d_in[8];
    const float* b2   = (const float*)d_in[9];
    const float* g2   = (const float*)d_in[10];
    const float* be2  = (const float*)d_in[11];
    const float* m2   = (const float*)d_in[12];
    const float* v2   = (const float*)d_in[13];
    float* out = (float*)d_out;

    // ws: h1s planar [21897216 sh], w2tf [743424 sh], w1t [16896 sh] ~45.3MB
    unsigned short* h1s  = (unsigned short*)d_ws;
    unsigned short* w2tf = h1s + 21897216;
    unsigned short* w1t  = w2tf + 743424;

    prep_w1t<<<dim3(66),   dim3(256), 0, stream>>>(w1, w1t);
    prep_w2f<<<dim3(2904), dim3(256), 0, stream>>>(w2, w2tf);
    zero_halo<<<dim3(324), dim3(256), 0, stream>>>(h1s);
    conv1_mfma<<<dim3(4, 41, 16), dim3(256), 0, stream>>>(
        x, xlen, w1t, b1, g1, be1, m1, v1, h1s);
    conv2_v6<<<dim3(352), dim3(256), 0, stream>>>(
        h1s, w2tf, xlen, b2, g2, be2, m2, v2, out);
}

// Round 7
// 243.907 us; speedup vs baseline: 1.3056x; 1.3056x over previous
//
#include <hip/hip_runtime.h>

typedef __attribute__((ext_vector_type(8))) __bf16 bf16x8;
typedef __attribute__((ext_vector_type(16))) float f32x16;

__device__ __forceinline__ unsigned short f2bf(float f) {
    unsigned int u = __float_as_uint(f);
    unsigned int r = (u + 0x7FFFu + ((u >> 16) & 1u)) >> 16;
    return (unsigned short)r;
}

// async global->LDS, 16B per lane (m97 pattern)
#define GLL16(gp, lp) \
    __builtin_amdgcn_global_load_lds( \
        (const __attribute__((address_space(1))) unsigned int*)(gp), \
        (__attribute__((address_space(3))) unsigned int*)(lp), 16, 0, 0)

// ---------------------------------------------------------------------------
// prep_w1t: w1 [32oc][1][41kh][11kw] f32 -> w1t [kw][oc][kh pad 48] bf16.
// ---------------------------------------------------------------------------
__global__ __launch_bounds__(256) void prep_w1t(const float* __restrict__ w1,
                                                unsigned short* __restrict__ w1t)
{
    const int t = blockIdx.x * 256 + threadIdx.x;   // 66 blocks -> exactly 16896
    const int k    = t % 48;
    const int rest = t / 48;
    const int oc   = rest & 31;
    const int kw   = rest >> 5;
    unsigned short v = 0;
    if (k < 41) v = f2bf(w1[(oc * 41 + k) * 11 + kw]);
    w1t[t] = v;
}

// ---------------------------------------------------------------------------
// prep_w2f: w2 [32oc][32ic][21][11] f32 -> dense A-fragments for 32x32x16:
//   w2tf[khp 0..24][kw 0..10][s 0..1][lane 0..63][8 bf16],  kh = khp - 2
// (zero outside [0,20]).  element: oc = l&31, ic = s*16 + (l>>5)*8 + j.
// ---------------------------------------------------------------------------
__global__ __launch_bounds__(256) void prep_w2f(const float* __restrict__ w2,
                                                unsigned short* __restrict__ w2tf)
{
    const int gid = blockIdx.x * 256 + threadIdx.x;  // 1100 blocks -> 281600 exact
    const int j  = gid & 7;
    const int l  = (gid >> 3) & 63;
    const int s  = (gid >> 9) & 1;
    const int ti = gid >> 10;        // 0..274
    const int khp = ti / 11;
    const int kw  = ti - khp * 11;
    const int kh  = khp - 2;
    const int oc  = l & 31;
    const int ic  = s * 16 + ((l >> 5) << 3) + j;
    unsigned short v = 0;
    if ((unsigned)kh <= 20u)
        v = f2bf(w2[((oc * 32 + ic) * 21 + kh) * 11 + kw]);
    w2tf[gid] = v;
}

// ---------------------------------------------------------------------------
// zero_halo: zero halo cols (c<5, c>=517) of planar h1s for all (n,r,icq).
// h1s layout: [n][r 0..80][icq 0..3][c 0..527][16B]  (plane = 8448 B)
// ---------------------------------------------------------------------------
__global__ __launch_bounds__(256) void zero_halo(unsigned short* __restrict__ h1s)
{
    const int id  = blockIdx.x * 256 + threadIdx.x;  // 324 blocks -> 82944 exact
    const int c16 = id & 15;
    const int q   = (id >> 4) & 3;
    const int nr  = id >> 6;                         // 0..1295
    const int c   = c16 < 5 ? c16 : 512 + c16;       // 0..4, 517..527
    uint4 z = {0u, 0u, 0u, 0u};
    *(uint4*)((char*)h1s + ((size_t)(nr * 4 + q) * 528 + c) * 16) = z;
}

// ---------------------------------------------------------------------------
// conv1_mfma: conv1 (41x11, s(2,2), p(20,5)) + bias + bn1 + clip + mask,
// 11 kw-taps of M=32(oc) x K=48(kh zero-pad) x N=ow GEMM on mfma_32x32x16_bf16.
// Epilogue transposes through LDS into the planar h1s layout.
// grid (4 ow-tiles, 41 oh-groups, 16 n), block 256.  (unchanged, verified)
// ---------------------------------------------------------------------------
__global__ __launch_bounds__(256) void conv1_mfma(
    const float* __restrict__ x, const int* __restrict__ xlen,
    const unsigned short* __restrict__ w1t,
    const float* __restrict__ b1, const float* __restrict__ g1,
    const float* __restrict__ be1, const float* __restrict__ m1,
    const float* __restrict__ v1,
    unsigned short* __restrict__ h1s)
{
    __shared__ uint4 lds4[2128];            // 34048 B: x-tile, then transpose buf
    char* lds = (char*)lds4;

    const int t  = threadIdx.x;
    const int bx = blockIdx.x;
    const int yi = blockIdx.y;
    const int n  = blockIdx.z;
    const int oh0 = ((yi >> 2) << 3) + (yi & 3);   // covers oh 0..80 with +4 pair
    const int len = xlen[n];

    const int l   = t & 63;
    const int w   = t >> 6;
    const int l31 = l & 31;
    const int lhi = l >> 5;

    char* h8 = (char*)h1s;
    const size_t rowpitch = 33792;          // 4 planes x 528 x 16B

    // dead strip: all cols masked -> store zeros, skip everything
    if (bx * 128 >= len) {
        #pragma unroll
        for (int it = 0; it < 4; ++it) {
            const int idx = t + it * 256;
            const int d1 = idx >> 9;
            const int q  = (idx >> 7) & 3;
            const int cl = idx & 127;
            const int oh = oh0 + 4 * d1;
            if (oh <= 80) {
                uint4 z = {0u, 0u, 0u, 0u};
                *(uint4*)(h8 + (size_t)(n * 81 + oh) * rowpitch + q * 8448
                          + (5 + (bx << 7) + cl) * 16) = z;
            }
        }
        return;
    }

    // ---- stage x: f32 -> bf16, transposed, swizzled ----
    const int cw   = t & 63;
    const int jrow = t >> 6;
    const int gr0  = 2 * oh0 - 20;
    const int gc0  = bx * 256 - 5;
    const float* xn = x + (size_t)n * 161 * 1024;
    #pragma unroll
    for (int cg = 0; cg < 5; ++cg) {
        const int c = cg * 64 + cw;
        if (c < 266) {
            const int gc = gc0 + c;
            const bool cok = (gc >= 0) && (gc < 1024);
            #pragma unroll
            for (int jj = 0; jj < 2; ++jj) {
                const int j = jrow + 4 * jj;       // chunk 0..6
                if (j < 7) {
                    unsigned int u[4];
                    #pragma unroll
                    for (int q = 0; q < 4; ++q) {
                        const int rA = gr0 + 8 * j + 2 * q;
                        float lo = 0.f, hi = 0.f;
                        if (cok && rA >= 0 && rA < 161)         lo = xn[(size_t)rA * 1024 + gc];
                        if (cok && rA + 1 >= 0 && rA + 1 < 161) hi = xn[(size_t)(rA + 1) * 1024 + gc];
                        u[q] = (unsigned int)f2bf(lo) | ((unsigned int)f2bf(hi) << 16);
                    }
                    uint4 val; val.x = u[0]; val.y = u[1]; val.z = u[2]; val.w = u[3];
                    *(uint4*)(lds + c * 128 + ((j ^ ((c >> 1) & 7)) << 4)) = val;
                }
            }
        }
    }
    __syncthreads();

    // ---- compute ----
    const int i = (w << 5) + l31;        // 0..127: ow within tile

    f32x16 acc0 = {}, acc1 = {};
    const char* w1tb = (const char*)w1t;
    #pragma unroll
    for (int kw = 0; kw < 11; ++kw) {
        const char* ap = w1tb + kw * 3072 + l31 * 96 + lhi * 16;
        const bf16x8 a0 = *(const bf16x8*)(ap);
        const bf16x8 a1 = *(const bf16x8*)(ap + 32);
        const bf16x8 a2 = *(const bf16x8*)(ap + 64);
        const int c = 2 * i + kw;
        const char* cb = lds + c * 128;
        const int sw = (c >> 1) & 7;
        const bf16x8 b00 = *(const bf16x8*)(cb + (((0 + lhi) ^ sw) << 4));
        const bf16x8 b01 = *(const bf16x8*)(cb + (((2 + lhi) ^ sw) << 4));
        const bf16x8 b02 = *(const bf16x8*)(cb + (((4 + lhi) ^ sw) << 4));
        const bf16x8 b10 = *(const bf16x8*)(cb + (((1 + lhi) ^ sw) << 4));
        const bf16x8 b11 = *(const bf16x8*)(cb + (((3 + lhi) ^ sw) << 4));
        const bf16x8 b12 = *(const bf16x8*)(cb + (((5 + lhi) ^ sw) << 4));
        acc0 = __builtin_amdgcn_mfma_f32_32x32x16_bf16(a0, b00, acc0, 0, 0, 0);
        acc0 = __builtin_amdgcn_mfma_f32_32x32x16_bf16(a1, b01, acc0, 0, 0, 0);
        acc0 = __builtin_amdgcn_mfma_f32_32x32x16_bf16(a2, b02, acc0, 0, 0, 0);
        acc1 = __builtin_amdgcn_mfma_f32_32x32x16_bf16(a0, b10, acc1, 0, 0, 0);
        acc1 = __builtin_amdgcn_mfma_f32_32x32x16_bf16(a1, b11, acc1, 0, 0, 0);
        acc1 = __builtin_amdgcn_mfma_f32_32x32x16_bf16(a2, b12, acc1, 0, 0, 0);
    }

    // ---- epilogue: bn1+clip+mask -> LDS transpose (planar) -> h1s ----
    __syncthreads();                     // x-tile reads done; reuse LDS
    const int ow  = bx * 128 + i;
    const bool vmask = ow < len;
    #pragma unroll
    for (int d1 = 0; d1 < 2; ++d1) {
        const int oh = oh0 + 4 * d1;
        if (oh <= 80) {
            #pragma unroll
            for (int q = 0; q < 4; ++q) {   // q = icq plane (oc>>3)
                float vv[4];
                #pragma unroll
                for (int rr = 0; rr < 4; ++rr) {
                    const int reg = (q << 2) + rr;
                    const int oc  = rr + (q << 3) + (lhi << 2);
                    const float s = g1[oc] * rsqrtf(v1[oc] + 1e-5f);
                    float val = ((d1 ? acc1[reg] : acc0[reg]) + b1[oc] - m1[oc]) * s + be1[oc];
                    val = fminf(fmaxf(val, 0.f), 20.f);
                    vv[rr] = vmask ? val : 0.f;
                }
                uint2 pk;
                pk.x = (unsigned int)f2bf(vv[0]) | ((unsigned int)f2bf(vv[1]) << 16);
                pk.y = (unsigned int)f2bf(vv[2]) | ((unsigned int)f2bf(vv[3]) << 16);
                *(uint2*)(lds + (((d1 << 2) + q) << 11) + i * 16 + lhi * 8) = pk;
            }
        }
    }
    __syncthreads();
    #pragma unroll
    for (int it = 0; it < 4; ++it) {
        const int idx = t + it * 256;    // 0..1023
        const int d1 = idx >> 9;
        const int q  = (idx >> 7) & 3;
        const int cl = idx & 127;
        const int oh = oh0 + 4 * d1;
        if (oh <= 80) {
            const uint4 v = *(const uint4*)(lds + (((d1 << 2) + q) << 11) + cl * 16);
            *(uint4*)(h8 + (size_t)(n * 81 + oh) * rowpitch + q * 8448
                      + (5 + (bx << 7) + cl) * 16) = v;
        }
    }
}

// ---------------------------------------------------------------------------
// conv2_v7: v5 economics (J=2, s-split, 128-col tile, 1344 blocks) +
// 4-deep LDS pipeline with counted vmcnt (T3/T4): stage row r+2, wait
// vmcnt(6) (= 2 rows x 3 DMA issues in flight), ONE raw s_barrier per iter
// (never vmcnt(0) in the loop). Multiplicative scramble (x605 mod 1344)
// balances live/dead blocks over CUs. s-reduction reuses staging LDS.
// ---------------------------------------------------------------------------
__global__ __launch_bounds__(256, 2) void conv2_v7(
    const unsigned short* __restrict__ h1s, const unsigned short* __restrict__ w2tf,
    const int* __restrict__ xlen,
    const float* __restrict__ b2, const float* __restrict__ g2,
    const float* __restrict__ be2, const float* __restrict__ m2,
    const float* __restrict__ v2, float* __restrict__ out)
{
    __shared__ char lbuf[4][9216];       // 4-deep: 4 planes x 144 cols x 16B

    const int t   = threadIdx.x;
    const int w   = t >> 6;
    const int l   = t & 63;
    const int l31 = l & 31;
    const int lhi = l >> 5;
    const int cg  = w >> 1;              // col-half (64 cols)
    const int s   = w & 1;               // K-half (ic 16s..16s+15)

    // scrambled bijective decode: lb = bid*605 mod 1344 (gcd=1)
    const int bid  = blockIdx.x;
    const int lb   = (bid * 605) % 1344;
    const int n    = lb / 84;
    const int r2   = lb - n * 84;
    const int by   = r2 >> 2;            // 0..20: oh2 pair {2by, 2by+1}
    const int bx   = r2 & 3;

    const int ow0 = bx << 7;
    const int len = xlen[n];

    if (ow0 >= len) {                    // fully masked col-tile: zeros only
        const int j   = w >> 1;
        const int cgz = w & 1;
        const int oh2 = 2 * by + j;
        if (oh2 <= 40) {
            #pragma unroll
            for (int g = 0; g < 2; ++g) {
                const int ow = ow0 + (cgz << 6) + (g << 5) + l31;
                #pragma unroll
                for (int reg = 0; reg < 16; ++reg) {
                    const int oc = (reg & 3) + ((reg >> 2) << 3) + (lhi << 2);
                    out[((size_t)(n * 32 + oc) * 41 + oh2) * 512 + ow] = 0.f;
                }
            }
        }
        return;
    }

    const int rlo = (4 * by - 10 > 0) ? 4 * by - 10 : 0;
    const int rhi = (4 * by + 12 < 80) ? 4 * by + 12 : 80;   // span 11..23 rows

    f32x16 acc[2][2] = {};               // [j][f]

    const char* h8 = (const char*)h1s;
    const size_t rowpitch = 33792;
    const char* nb = h8 + (size_t)(n * 81) * rowpitch + (size_t)(ow0 << 4);

    // stage: 4 planes x 144 cols x 16B; wave w stages plane w (3 DMA issues)
    #define STAGE(r, buf) do { \
        const char* g_ = nb + (size_t)(r) * rowpitch + w * 8448; \
        char* d_ = &lbuf[buf][0] + w * 2304; \
        GLL16(g_ + l * 16,        d_ + l * 16); \
        GLL16(g_ + 1024 + l * 16, d_ + 1024 + l * 16); \
        if (l < 16) GLL16(g_ + 2048 + l * 16, d_ + 2048 + l * 16); \
    } while (0)

    // prologue: fill pipeline (rows rlo, rlo+1, rlo+2; span >= 11 so in-range)
    STAGE(rlo,     0);
    STAGE(rlo + 1, 1);
    STAGE(rlo + 2, 2);

    const char* w8v = (const char*)w2tf;
    for (int r = rlo; r <= rhi; ++r) {
        {   // stage row r+2 (clamped dup at tail keeps vmcnt count uniform)
            const int rs = (r + 2 <= rhi) ? r + 2 : rhi;
            if (r > rlo) STAGE(rs, (r - rlo + 2) & 3);
        }
        // row r's 3 DMAs are the oldest beyond the 6 in flight (rows r+1, r+2)
        asm volatile("s_waitcnt vmcnt(6)" ::: "memory");
        __builtin_amdgcn_s_barrier();
        __builtin_amdgcn_sched_barrier(0);

        const char* lb8 = &lbuf[(r - rlo) & 3][0];
        const int khb = r - 4 * by + 10;           // 0..22
        #pragma unroll
        for (int kw = 0; kw < 11; ++kw) {
            const char* bp = lb8 + (2 * s + lhi) * 2304 + ((cg << 6) + l31 + kw) * 16;
            const bf16x8 B0 = *(const bf16x8*)(bp);
            const bf16x8 B1 = *(const bf16x8*)(bp + 512);
            #pragma unroll
            for (int j = 0; j < 2; ++j) {
                const int khp = khb + 2 - 2 * j;   // 0..24
                const bf16x8 A = *(const bf16x8*)(w8v
                    + (size_t)(((khp * 11 + kw) * 2 + s) << 10) + (l << 4));
                acc[j][0] = __builtin_amdgcn_mfma_f32_32x32x16_bf16(A, B0, acc[j][0], 0, 0, 0);
                acc[j][1] = __builtin_amdgcn_mfma_f32_32x32x16_bf16(A, B1, acc[j][1], 0, 0, 0);
            }
        }
    }
    #undef STAGE

    // ---- cross-wave s-reduction via LDS (reuses staging buffers, 32KB) ----
    __syncthreads();
    char* red = &lbuf[0][0];
    if (s == 1) {
        #pragma unroll
        for (int j = 0; j < 2; ++j) {
            #pragma unroll
            for (int f = 0; f < 2; ++f) {
                char* dst = red + ((((cg << 1) + j) << 1) + f) * 4096 + l * 16;
                #pragma unroll
                for (int q = 0; q < 4; ++q) {
                    float4 v;
                    v.x = acc[j][f][q * 4 + 0]; v.y = acc[j][f][q * 4 + 1];
                    v.z = acc[j][f][q * 4 + 2]; v.w = acc[j][f][q * 4 + 3];
                    *(float4*)(dst + q * 1024) = v;
                }
            }
        }
    }
    __syncthreads();
    if (s == 1) return;

    // ---- epilogue (s==0 waves): add partner acc, bn2 + clip + mask ----
    #pragma unroll
    for (int j = 0; j < 2; ++j) {
        const int oh2 = 2 * by + j;
        if (oh2 <= 40) {
            #pragma unroll
            for (int f = 0; f < 2; ++f) {
                const char* src = red + ((((cg << 1) + j) << 1) + f) * 4096 + l * 16;
                float pr[16];
                #pragma unroll
                for (int q = 0; q < 4; ++q) {
                    const float4 v = *(const float4*)(src + q * 1024);
                    pr[q * 4 + 0] = v.x; pr[q * 4 + 1] = v.y;
                    pr[q * 4 + 2] = v.z; pr[q * 4 + 3] = v.w;
                }
                const int ow = ow0 + (cg << 6) + (f << 5) + l31;
                const bool valid = ow < len;
                #pragma unroll
                for (int reg = 0; reg < 16; ++reg) {
                    const int oc = (reg & 3) + ((reg >> 2) << 3) + (lhi << 2);
                    const float sc = g2[oc] * rsqrtf(v2[oc] + 1e-5f);
                    float val = (acc[j][f][reg] + pr[reg] + b2[oc] - m2[oc]) * sc + be2[oc];
                    val = fminf(fmaxf(val, 0.f), 20.f);
                    if (!valid) val = 0.f;
                    out[((size_t)(n * 32 + oc) * 41 + oh2) * 512 + ow] = val;
                }
            }
        }
    }
}

extern "C" void kernel_launch(void* const* d_in, const int* in_sizes, int n_in,
                              void* d_out, int out_size, void* d_ws, size_t ws_size,
                              hipStream_t stream) {
    const float* x    = (const float*)d_in[0];
    const int*   xlen = (const int*)  d_in[1];
    const float* w1   = (const float*)d_in[2];
    const float* b1   = (const float*)d_in[3];
    const float* g1   = (const float*)d_in[4];
    const float* be1  = (const float*)d_in[5];
    const float* m1   = (const float*)d_in[6];
    const float* v1   = (const float*)d_in[7];
    const float* w2   = (const float*)d_in[8];
    const float* b2   = (const float*)d_in[9];
    const float* g2   = (const float*)d_in[10];
    const float* be2  = (const float*)d_in[11];
    const float* m2   = (const float*)d_in[12];
    const float* v2   = (const float*)d_in[13];
    float* out = (float*)d_out;

    // ws: h1s planar [21897216 sh], w2tf [281600 sh], w1t [16896 sh] ~44.4MB
    unsigned short* h1s  = (unsigned short*)d_ws;
    unsigned short* w2tf = h1s + 21897216;
    unsigned short* w1t  = w2tf + 281600;

    prep_w1t<<<dim3(66),   dim3(256), 0, stream>>>(w1, w1t);
    prep_w2f<<<dim3(1100), dim3(256), 0, stream>>>(w2, w2tf);
    zero_halo<<<dim3(324), dim3(256), 0, stream>>>(h1s);
    conv1_mfma<<<dim3(4, 41, 16), dim3(256), 0, stream>>>(
        x, xlen, w1t, b1, g1, be1, m1, v1, h1s);
    conv2_v7<<<dim3(1344), dim3(256), 0, stream>>>(
        h1s, w2tf, xlen, b2, g2, be2, m2, v2, out);
}

// Round 9
// 235.118 us; speedup vs baseline: 1.3544x; 1.0374x over previous
//
#include <hip/hip_runtime.h>

typedef __attribute__((ext_vector_type(8))) __bf16 bf16x8;
typedef __attribute__((ext_vector_type(16))) float f32x16;

__device__ __forceinline__ unsigned short f2bf(float f) {
    unsigned int u = __float_as_uint(f);
    unsigned int r = (u + 0x7FFFu + ((u >> 16) & 1u)) >> 16;
    return (unsigned short)r;
}

// async global->LDS, 16B per lane (m97 pattern)
#define GLL16(gp, lp) \
    __builtin_amdgcn_global_load_lds( \
        (const __attribute__((address_space(1))) unsigned int*)(gp), \
        (__attribute__((address_space(3))) unsigned int*)(lp), 16, 0, 0)

// ---------------------------------------------------------------------------
// prep_w1t: w1 [32oc][1][41kh][11kw] f32 -> w1t [kw][oc][kh pad 48] bf16.
// ---------------------------------------------------------------------------
__global__ __launch_bounds__(256) void prep_w1t(const float* __restrict__ w1,
                                                unsigned short* __restrict__ w1t)
{
    const int t = blockIdx.x * 256 + threadIdx.x;   // 66 blocks -> exactly 16896
    const int k    = t % 48;
    const int rest = t / 48;
    const int oc   = rest & 31;
    const int kw   = rest >> 5;
    unsigned short v = 0;
    if (k < 41) v = f2bf(w1[(oc * 41 + k) * 11 + kw]);
    w1t[t] = v;
}

// ---------------------------------------------------------------------------
// prep_w2f: w2 [32oc][32ic][21][11] f32 -> dense A-fragments for 32x32x16:
//   w2tf[khp 0..24][kw 0..10][s 0..1][lane 0..63][8 bf16],  kh = khp - 2
// (zero outside [0,20]).  element: oc = l&31, ic = s*16 + (l>>5)*8 + j.
// ---------------------------------------------------------------------------
__global__ __launch_bounds__(256) void prep_w2f(const float* __restrict__ w2,
                                                unsigned short* __restrict__ w2tf)
{
    const int gid = blockIdx.x * 256 + threadIdx.x;  // 1100 blocks -> 281600 exact
    const int j  = gid & 7;
    const int l  = (gid >> 3) & 63;
    const int s  = (gid >> 9) & 1;
    const int ti = gid >> 10;        // 0..274
    const int khp = ti / 11;
    const int kw  = ti - khp * 11;
    const int kh  = khp - 2;
    const int oc  = l & 31;
    const int ic  = s * 16 + ((l >> 5) << 3) + j;
    unsigned short v = 0;
    if ((unsigned)kh <= 20u)
        v = f2bf(w2[((oc * 32 + ic) * 21 + kh) * 11 + kw]);
    w2tf[gid] = v;
}

// ---------------------------------------------------------------------------
// zero_halo: zero halo cols (c<5, c>=517) of planar h1s for all (n,r,icq).
// h1s layout: [n][r 0..80][icq 0..3][c 0..527][16B]  (plane = 8448 B)
// ---------------------------------------------------------------------------
__global__ __launch_bounds__(256) void zero_halo(unsigned short* __restrict__ h1s)
{
    const int id  = blockIdx.x * 256 + threadIdx.x;  // 324 blocks -> 82944 exact
    const int c16 = id & 15;
    const int q   = (id >> 4) & 3;
    const int nr  = id >> 6;                         // 0..1295
    const int c   = c16 < 5 ? c16 : 512 + c16;       // 0..4, 517..527
    uint4 z = {0u, 0u, 0u, 0u};
    *(uint4*)((char*)h1s + ((size_t)(nr * 4 + q) * 528 + c) * 16) = z;
}

// ---------------------------------------------------------------------------
// conv1_mfma: conv1 (41x11, s(2,2), p(20,5)) + bias + bn1 + clip + mask,
// 11 kw-taps of M=32(oc) x K=48(kh zero-pad) x N=ow GEMM on mfma_32x32x16_bf16.
// Epilogue transposes through LDS into the planar h1s layout.
// grid (4 ow-tiles, 41 oh-groups, 16 n), block 256.  (unchanged, verified)
// ---------------------------------------------------------------------------
__global__ __launch_bounds__(256) void conv1_mfma(
    const float* __restrict__ x, const int* __restrict__ xlen,
    const unsigned short* __restrict__ w1t,
    const float* __restrict__ b1, const float* __restrict__ g1,
    const float* __restrict__ be1, const float* __restrict__ m1,
    const float* __restrict__ v1,
    unsigned short* __restrict__ h1s)
{
    __shared__ uint4 lds4[2128];            // 34048 B: x-tile, then transpose buf
    char* lds = (char*)lds4;

    const int t  = threadIdx.x;
    const int bx = blockIdx.x;
    const int yi = blockIdx.y;
    const int n  = blockIdx.z;
    const int oh0 = ((yi >> 2) << 3) + (yi & 3);   // covers oh 0..80 with +4 pair
    const int len = xlen[n];

    const int l   = t & 63;
    const int w   = t >> 6;
    const int l31 = l & 31;
    const int lhi = l >> 5;

    char* h8 = (char*)h1s;
    const size_t rowpitch = 33792;          // 4 planes x 528 x 16B

    // dead strip: all cols masked -> store zeros, skip everything
    if (bx * 128 >= len) {
        #pragma unroll
        for (int it = 0; it < 4; ++it) {
            const int idx = t + it * 256;
            const int d1 = idx >> 9;
            const int q  = (idx >> 7) & 3;
            const int cl = idx & 127;
            const int oh = oh0 + 4 * d1;
            if (oh <= 80) {
                uint4 z = {0u, 0u, 0u, 0u};
                *(uint4*)(h8 + (size_t)(n * 81 + oh) * rowpitch + q * 8448
                          + (5 + (bx << 7) + cl) * 16) = z;
            }
        }
        return;
    }

    // ---- stage x: f32 -> bf16, transposed, swizzled ----
    const int cw   = t & 63;
    const int jrow = t >> 6;
    const int gr0  = 2 * oh0 - 20;
    const int gc0  = bx * 256 - 5;
    const float* xn = x + (size_t)n * 161 * 1024;
    #pragma unroll
    for (int cg = 0; cg < 5; ++cg) {
        const int c = cg * 64 + cw;
        if (c < 266) {
            const int gc = gc0 + c;
            const bool cok = (gc >= 0) && (gc < 1024);
            #pragma unroll
            for (int jj = 0; jj < 2; ++jj) {
                const int j = jrow + 4 * jj;       // chunk 0..6
                if (j < 7) {
                    unsigned int u[4];
                    #pragma unroll
                    for (int q = 0; q < 4; ++q) {
                        const int rA = gr0 + 8 * j + 2 * q;
                        float lo = 0.f, hi = 0.f;
                        if (cok && rA >= 0 && rA < 161)         lo = xn[(size_t)rA * 1024 + gc];
                        if (cok && rA + 1 >= 0 && rA + 1 < 161) hi = xn[(size_t)(rA + 1) * 1024 + gc];
                        u[q] = (unsigned int)f2bf(lo) | ((unsigned int)f2bf(hi) << 16);
                    }
                    uint4 val; val.x = u[0]; val.y = u[1]; val.z = u[2]; val.w = u[3];
                    *(uint4*)(lds + c * 128 + ((j ^ ((c >> 1) & 7)) << 4)) = val;
                }
            }
        }
    }
    __syncthreads();

    // ---- compute ----
    const int i = (w << 5) + l31;        // 0..127: ow within tile

    f32x16 acc0 = {}, acc1 = {};
    const char* w1tb = (const char*)w1t;
    #pragma unroll
    for (int kw = 0; kw < 11; ++kw) {
        const char* ap = w1tb + kw * 3072 + l31 * 96 + lhi * 16;
        const bf16x8 a0 = *(const bf16x8*)(ap);
        const bf16x8 a1 = *(const bf16x8*)(ap + 32);
        const bf16x8 a2 = *(const bf16x8*)(ap + 64);
        const int c = 2 * i + kw;
        const char* cb = lds + c * 128;
        const int sw = (c >> 1) & 7;
        const bf16x8 b00 = *(const bf16x8*)(cb + (((0 + lhi) ^ sw) << 4));
        const bf16x8 b01 = *(const bf16x8*)(cb + (((2 + lhi) ^ sw) << 4));
        const bf16x8 b02 = *(const bf16x8*)(cb + (((4 + lhi) ^ sw) << 4));
        const bf16x8 b10 = *(const bf16x8*)(cb + (((1 + lhi) ^ sw) << 4));
        const bf16x8 b11 = *(const bf16x8*)(cb + (((3 + lhi) ^ sw) << 4));
        const bf16x8 b12 = *(const bf16x8*)(cb + (((5 + lhi) ^ sw) << 4));
        acc0 = __builtin_amdgcn_mfma_f32_32x32x16_bf16(a0, b00, acc0, 0, 0, 0);
        acc0 = __builtin_amdgcn_mfma_f32_32x32x16_bf16(a1, b01, acc0, 0, 0, 0);
        acc0 = __builtin_amdgcn_mfma_f32_32x32x16_bf16(a2, b02, acc0, 0, 0, 0);
        acc1 = __builtin_amdgcn_mfma_f32_32x32x16_bf16(a0, b10, acc1, 0, 0, 0);
        acc1 = __builtin_amdgcn_mfma_f32_32x32x16_bf16(a1, b11, acc1, 0, 0, 0);
        acc1 = __builtin_amdgcn_mfma_f32_32x32x16_bf16(a2, b12, acc1, 0, 0, 0);
    }

    // ---- epilogue: bn1+clip+mask -> LDS transpose (planar) -> h1s ----
    __syncthreads();                     // x-tile reads done; reuse LDS
    const int ow  = bx * 128 + i;
    const bool vmask = ow < len;
    #pragma unroll
    for (int d1 = 0; d1 < 2; ++d1) {
        const int oh = oh0 + 4 * d1;
        if (oh <= 80) {
            #pragma unroll
            for (int q = 0; q < 4; ++q) {   // q = icq plane (oc>>3)
                float vv[4];
                #pragma unroll
                for (int rr = 0; rr < 4; ++rr) {
                    const int reg = (q << 2) + rr;
                    const int oc  = rr + (q << 3) + (lhi << 2);
                    const float s = g1[oc] * rsqrtf(v1[oc] + 1e-5f);
                    float val = ((d1 ? acc1[reg] : acc0[reg]) + b1[oc] - m1[oc]) * s + be1[oc];
                    val = fminf(fmaxf(val, 0.f), 20.f);
                    vv[rr] = vmask ? val : 0.f;
                }
                uint2 pk;
                pk.x = (unsigned int)f2bf(vv[0]) | ((unsigned int)f2bf(vv[1]) << 16);
                pk.y = (unsigned int)f2bf(vv[2]) | ((unsigned int)f2bf(vv[3]) << 16);
                *(uint2*)(lds + (((d1 << 2) + q) << 11) + i * 16 + lhi * 8) = pk;
            }
        }
    }
    __syncthreads();
    #pragma unroll
    for (int it = 0; it < 4; ++it) {
        const int idx = t + it * 256;    // 0..1023
        const int d1 = idx >> 9;
        const int q  = (idx >> 7) & 3;
        const int cl = idx & 127;
        const int oh = oh0 + 4 * d1;
        if (oh <= 80) {
            const uint4 v = *(const uint4*)(lds + (((d1 << 2) + q) << 11) + cl * 16);
            *(uint4*)(h8 + (size_t)(n * 81 + oh) * rowpitch + q * 8448
                      + (5 + (bx << 7) + cl) * 16) = v;
        }
    }
}

// ---------------------------------------------------------------------------
// conv2_v9: v7 skeleton (J=2, s-split, 128-col tile, 1344 blocks, x605
// scramble) + per-row A-REGISTER BURST: all 22 A-frags loaded into VGPRs
// before the MFMA section (one L2 latency/row instead of 22), pinned with
// sched_barrier(0). Sync: prologue stages rows rlo/rlo+1 + __syncthreads;
// each iter stages r+2 into a 4-deep ring, then raw s_barrier only (buffer
// r+2 is retired by iter r+1's own last-A s_waitcnt; in-order vmcnt).
// ---------------------------------------------------------------------------
__global__ __launch_bounds__(256, 2) void conv2_v9(
    const unsigned short* __restrict__ h1s, const unsigned short* __restrict__ w2tf,
    const int* __restrict__ xlen,
    const float* __restrict__ b2, const float* __restrict__ g2,
    const float* __restrict__ be2, const float* __restrict__ m2,
    const float* __restrict__ v2, float* __restrict__ out)
{
    __shared__ char lbuf[4][9216];       // 4-deep ring: 4 planes x 144 cols x 16B

    const int t   = threadIdx.x;
    const int w   = t >> 6;
    const int l   = t & 63;
    const int l31 = l & 31;
    const int lhi = l >> 5;
    const int cg  = w >> 1;              // col-half (64 cols)
    const int s   = w & 1;               // K-half (ic 16s..16s+15)

    // scrambled bijective decode: lb = bid*605 mod 1344 (gcd=1)
    const int bid  = blockIdx.x;
    const int lb   = (bid * 605) % 1344;
    const int n    = lb / 84;
    const int r2   = lb - n * 84;
    const int by   = r2 >> 2;            // 0..20: oh2 pair {2by, 2by+1}
    const int bx   = r2 & 3;

    const int ow0 = bx << 7;
    const int len = xlen[n];

    if (ow0 >= len) {                    // fully masked col-tile: zeros only
        const int j   = w >> 1;
        const int cgz = w & 1;
        const int oh2 = 2 * by + j;
        if (oh2 <= 40) {
            #pragma unroll
            for (int g = 0; g < 2; ++g) {
                const int ow = ow0 + (cgz << 6) + (g << 5) + l31;
                #pragma unroll
                for (int reg = 0; reg < 16; ++reg) {
                    const int oc = (reg & 3) + ((reg >> 2) << 3) + (lhi << 2);
                    out[((size_t)(n * 32 + oc) * 41 + oh2) * 512 + ow] = 0.f;
                }
            }
        }
        return;
    }

    const int rlo = (4 * by - 10 > 0) ? 4 * by - 10 : 0;
    const int rhi = (4 * by + 12 < 80) ? 4 * by + 12 : 80;   // span >= 11 rows

    f32x16 acc[2][2] = {};               // [j][f]

    const char* h8 = (const char*)h1s;
    const size_t rowpitch = 33792;
    const char* nb = h8 + (size_t)(n * 81) * rowpitch + (size_t)(ow0 << 4);

    // stage: 4 planes x 144 cols x 16B; wave w stages plane w (3 DMA issues)
    #define STAGE(r, buf) do { \
        const char* g_ = nb + (size_t)(r) * rowpitch + w * 8448; \
        char* d_ = &lbuf[buf][0] + w * 2304; \
        GLL16(g_ + l * 16,        d_ + l * 16); \
        GLL16(g_ + 1024 + l * 16, d_ + 1024 + l * 16); \
        if (l < 16) GLL16(g_ + 2048 + l * 16, d_ + 2048 + l * 16); \
    } while (0)

    // prologue: buffers 0,1 staged and fully drained
    STAGE(rlo,     0);
    STAGE(rlo + 1, 1);
    __syncthreads();

    const char* w8v = (const char*)w2tf;
    for (int r = rlo; r <= rhi; ++r) {
        const int khb = r - 4 * by + 10;           // 0..22
        // ---- A-burst: all 22 frags for this row into registers ----
        const char* aj0 = w8v + (size_t)((((khb + 2) * 11) * 2 + s) << 10) + (l << 4);
        const char* aj1 = w8v + (size_t)(((khb * 11) * 2 + s) << 10) + (l << 4);
        bf16x8 Ar0[11], Ar1[11];
        #pragma unroll
        for (int kw = 0; kw < 11; ++kw) {
            Ar0[kw] = *(const bf16x8*)(aj0 + (kw << 11));
            Ar1[kw] = *(const bf16x8*)(aj1 + (kw << 11));
        }
        if (r + 2 <= rhi) STAGE(r + 2, (r - rlo + 2) & 3);
        __builtin_amdgcn_sched_barrier(0);         // pin loads above
        __builtin_amdgcn_s_barrier();
        __builtin_amdgcn_sched_barrier(0);         // pin ds_reads/MFMAs below

        const char* lb8 = &lbuf[(r - rlo) & 3][0];
        #pragma unroll
        for (int kw = 0; kw < 11; ++kw) {
            const char* bp = lb8 + (2 * s + lhi) * 2304 + ((cg << 6) + l31 + kw) * 16;
            const bf16x8 B0 = *(const bf16x8*)(bp);
            const bf16x8 B1 = *(const bf16x8*)(bp + 512);
            acc[0][0] = __builtin_amdgcn_mfma_f32_32x32x16_bf16(Ar0[kw], B0, acc[0][0], 0, 0, 0);
            acc[0][1] = __builtin_amdgcn_mfma_f32_32x32x16_bf16(Ar0[kw], B1, acc[0][1], 0, 0, 0);
            acc[1][0] = __builtin_amdgcn_mfma_f32_32x32x16_bf16(Ar1[kw], B0, acc[1][0], 0, 0, 0);
            acc[1][1] = __builtin_amdgcn_mfma_f32_32x32x16_bf16(Ar1[kw], B1, acc[1][1], 0, 0, 0);
        }
    }
    #undef STAGE

    // ---- cross-wave s-reduction via LDS (reuses staging buffers, 32KB) ----
    __syncthreads();
    char* red = &lbuf[0][0];
    if (s == 1) {
        #pragma unroll
        for (int j = 0; j < 2; ++j) {
            #pragma unroll
            for (int f = 0; f < 2; ++f) {
                char* dst = red + ((((cg << 1) + j) << 1) + f) * 4096 + l * 16;
                #pragma unroll
                for (int q = 0; q < 4; ++q) {
                    float4 v;
                    v.x = acc[j][f][q * 4 + 0]; v.y = acc[j][f][q * 4 + 1];
                    v.z = acc[j][f][q * 4 + 2]; v.w = acc[j][f][q * 4 + 3];
                    *(float4*)(dst + q * 1024) = v;
                }
            }
        }
    }
    __syncthreads();
    if (s == 1) return;

    // ---- epilogue (s==0 waves): add partner acc, bn2 + clip + mask ----
    #pragma unroll
    for (int j = 0; j < 2; ++j) {
        const int oh2 = 2 * by + j;
        if (oh2 <= 40) {
            #pragma unroll
            for (int f = 0; f < 2; ++f) {
                const char* src = red + ((((cg << 1) + j) << 1) + f) * 4096 + l * 16;
                float pr[16];
                #pragma unroll
                for (int q = 0; q < 4; ++q) {
                    const float4 v = *(const float4*)(src + q * 1024);
                    pr[q * 4 + 0] = v.x; pr[q * 4 + 1] = v.y;
                    pr[q * 4 + 2] = v.z; pr[q * 4 + 3] = v.w;
                }
                const int ow = ow0 + (cg << 6) + (f << 5) + l31;
                const bool valid = ow < len;
                #pragma unroll
                for (int reg = 0; reg < 16; ++reg) {
                    const int oc = (reg & 3) + ((reg >> 2) << 3) + (lhi << 2);
                    const float sc = g2[oc] * rsqrtf(v2[oc] + 1e-5f);
                    float val = (acc[j][f][reg] + pr[reg] + b2[oc] - m2[oc]) * sc + be2[oc];
                    val = fminf(fmaxf(val, 0.f), 20.f);
                    if (!valid) val = 0.f;
                    out[((size_t)(n * 32 + oc) * 41 + oh2) * 512 + ow] = val;
                }
            }
        }
    }
}

extern "C" void kernel_launch(void* const* d_in, const int* in_sizes, int n_in,
                              void* d_out, int out_size, void* d_ws, size_t ws_size,
                              hipStream_t stream) {
    const float* x    = (const float*)d_in[0];
    const int*   xlen = (const int*)  d_in[1];
    const float* w1   = (const float*)d_in[2];
    const float* b1   = (const float*)d_in[3];
    const float* g1   = (const float*)d_in[4];
    const float* be1  = (const float*)d_in[5];
    const float* m1   = (const float*)d_in[6];
    const float* v1   = (const float*)d_in[7];
    const float* w2   = (const float*)d_in[8];
    const float* b2   = (const float*)d_in[9];
    const float* g2   = (const float*)d_in[10];
    const float* be2  = (const float*)d_in[11];
    const float* m2   = (const float*)d_in[12];
    const float* v2   = (const float*)d_in[13];
    float* out = (float*)d_out;

    // ws: h1s planar [21897216 sh], w2tf [281600 sh], w1t [16896 sh] ~44.4MB
    unsigned short* h1s  = (unsigned short*)d_ws;
    unsigned short* w2tf = h1s + 21897216;
    unsigned short* w1t  = w2tf + 281600;

    prep_w1t<<<dim3(66),   dim3(256), 0, stream>>>(w1, w1t);
    prep_w2f<<<dim3(1100), dim3(256), 0, stream>>>(w2, w2tf);
    zero_halo<<<dim3(324), dim3(256), 0, stream>>>(h1s);
    conv1_mfma<<<dim3(4, 41, 16), dim3(256), 0, stream>>>(
        x, xlen, w1t, b1, g1, be1, m1, v1, h1s);
    conv2_v9<<<dim3(1344), dim3(256), 0, stream>>>(
        h1s, w2tf, xlen, b2, g2, be2, m2, v2, out);
}

// Round 11
// 204.718 us; speedup vs baseline: 1.5555x; 1.1485x over previous
//
#include <hip/hip_runtime.h>

typedef __attribute__((ext_vector_type(8))) __bf16 bf16x8;
typedef __attribute__((ext_vector_type(16))) float f32x16;

__device__ __forceinline__ unsigned short f2bf(float f) {
    unsigned int u = __float_as_uint(f);
    unsigned int r = (u + 0x7FFFu + ((u >> 16) & 1u)) >> 16;
    return (unsigned short)r;
}

// async global->LDS, 16B per lane (m97 pattern)
#define GLL16(gp, lp) \
    __builtin_amdgcn_global_load_lds( \
        (const __attribute__((address_space(1))) unsigned int*)(gp), \
        (__attribute__((address_space(3))) unsigned int*)(lp), 16, 0, 0)

// ---------------------------------------------------------------------------
// prep_w1t: w1 [32oc][1][41kh][11kw] f32 -> w1t [kw][oc][kh pad 48] bf16.
// ---------------------------------------------------------------------------
__global__ __launch_bounds__(256) void prep_w1t(const float* __restrict__ w1,
                                                unsigned short* __restrict__ w1t)
{
    const int t = blockIdx.x * 256 + threadIdx.x;   // 66 blocks -> exactly 16896
    const int k    = t % 48;
    const int rest = t / 48;
    const int oc   = rest & 31;
    const int kw   = rest >> 5;
    unsigned short v = 0;
    if (k < 41) v = f2bf(w1[(oc * 41 + k) * 11 + kw]);
    w1t[t] = v;
}

// ---------------------------------------------------------------------------
// prep_w2f: w2 [32oc][32ic][21][11] f32 -> dense A-fragments for 32x32x16:
//   w2tf[khpp 0..30][kw 0..10][s 0..1][lane 0..63][8 bf16],  kh = khpp - 4
// (zero outside [0,20]; pad covers sliding-window prologue).
// element: oc = l&31, ic = s*16 + (l>>5)*8 + j.
// ---------------------------------------------------------------------------
__global__ __launch_bounds__(256) void prep_w2f(const float* __restrict__ w2,
                                                unsigned short* __restrict__ w2tf)
{
    const int gid = blockIdx.x * 256 + threadIdx.x;  // 1364 blocks -> 349184 exact
    const int j  = gid & 7;
    const int l  = (gid >> 3) & 63;
    const int s  = (gid >> 9) & 1;
    const int ti = gid >> 10;        // 0..340
    const int khpp = ti / 11;
    const int kw   = ti - khpp * 11;
    const int kh   = khpp - 4;
    const int oc   = l & 31;
    const int ic   = s * 16 + ((l >> 5) << 3) + j;
    unsigned short v = 0;
    if ((unsigned)kh <= 20u)
        v = f2bf(w2[((oc * 32 + ic) * 21 + kh) * 11 + kw]);
    w2tf[gid] = v;
}

// ---------------------------------------------------------------------------
// zero_halo: zero halo cols (11..15, 528..532) of planar h1s for all (n,r,q).
// h1s layout: [n][r 0..80][q 0..3][c 0..543][16B]  (plane = 8704 B,
// row pitch = 34816 B; real outputs live at shifted cols 16..527)
// ---------------------------------------------------------------------------
__global__ __launch_bounds__(256) void zero_halo(unsigned short* __restrict__ h1s)
{
    const int id = blockIdx.x * 256 + threadIdx.x;   // 203 blocks, 51840 items
    if (id >= 51840) return;
    const int k  = id % 10;
    const int qq = (id / 10) & 3;
    const int nr = id / 40;                          // 0..1295
    const int c  = (k < 5) ? 11 + k : 523 + k;       // 11..15, 528..532
    uint4 z = {0u, 0u, 0u, 0u};
    *(uint4*)((char*)h1s + ((size_t)(nr * 4 + qq) * 544 + c) * 16) = z;
}

// ---------------------------------------------------------------------------
// conv1_mfma: conv1 (41x11, s(2,2), p(20,5)) + bias + bn1 + clip + mask,
// 11 kw-taps of M=32(oc) x K=48(kh zero-pad) x N=ow GEMM on mfma_32x32x16_bf16.
// Epilogue transposes through LDS into the planar 544-wide h1s layout.
// grid (4 ow-tiles, 41 oh-groups, 16 n), block 256.
// ---------------------------------------------------------------------------
__global__ __launch_bounds__(256) void conv1_mfma(
    const float* __restrict__ x, const int* __restrict__ xlen,
    const unsigned short* __restrict__ w1t,
    const float* __restrict__ b1, const float* __restrict__ g1,
    const float* __restrict__ be1, const float* __restrict__ m1,
    const float* __restrict__ v1,
    unsigned short* __restrict__ h1s)
{
    __shared__ uint4 lds4[2128];            // 34048 B: x-tile, then transpose buf
    char* lds = (char*)lds4;

    const int t  = threadIdx.x;
    const int bx = blockIdx.x;
    const int yi = blockIdx.y;
    const int n  = blockIdx.z;
    const int oh0 = ((yi >> 2) << 3) + (yi & 3);   // covers oh 0..80 with +4 pair
    const int len = xlen[n];

    const int l   = t & 63;
    const int w   = t >> 6;
    const int l31 = l & 31;
    const int lhi = l >> 5;

    char* h8 = (char*)h1s;
    const size_t rowpitch = 34816;          // 4 planes x 544 x 16B

    // dead strip: all cols masked -> store zeros, skip everything
    if (bx * 128 >= len) {
        #pragma unroll
        for (int it = 0; it < 4; ++it) {
            const int idx = t + it * 256;
            const int d1 = idx >> 9;
            const int q  = (idx >> 7) & 3;
            const int cl = idx & 127;
            const int oh = oh0 + 4 * d1;
            if (oh <= 80) {
                uint4 z = {0u, 0u, 0u, 0u};
                *(uint4*)(h8 + (size_t)(n * 81 + oh) * rowpitch + q * 8704
                          + (16 + (bx << 7) + cl) * 16) = z;
            }
        }
        return;
    }

    // ---- stage x: f32 -> bf16, transposed, swizzled ----
    const int cw   = t & 63;
    const int jrow = t >> 6;
    const int gr0  = 2 * oh0 - 20;
    const int gc0  = bx * 256 - 5;
    const float* xn = x + (size_t)n * 161 * 1024;
    #pragma unroll
    for (int cg = 0; cg < 5; ++cg) {
        const int c = cg * 64 + cw;
        if (c < 266) {
            const int gc = gc0 + c;
            const bool cok = (gc >= 0) && (gc < 1024);
            #pragma unroll
            for (int jj = 0; jj < 2; ++jj) {
                const int j = jrow + 4 * jj;       // chunk 0..6
                if (j < 7) {
                    unsigned int u[4];
                    #pragma unroll
                    for (int q = 0; q < 4; ++q) {
                        const int rA = gr0 + 8 * j + 2 * q;
                        float lo = 0.f, hi = 0.f;
                        if (cok && rA >= 0 && rA < 161)         lo = xn[(size_t)rA * 1024 + gc];
                        if (cok && rA + 1 >= 0 && rA + 1 < 161) hi = xn[(size_t)(rA + 1) * 1024 + gc];
                        u[q] = (unsigned int)f2bf(lo) | ((unsigned int)f2bf(hi) << 16);
                    }
                    uint4 val; val.x = u[0]; val.y = u[1]; val.z = u[2]; val.w = u[3];
                    *(uint4*)(lds + c * 128 + ((j ^ ((c >> 1) & 7)) << 4)) = val;
                }
            }
        }
    }
    __syncthreads();

    // ---- compute ----
    const int i = (w << 5) + l31;        // 0..127: ow within tile

    f32x16 acc0 = {}, acc1 = {};
    const char* w1tb = (const char*)w1t;
    #pragma unroll
    for (int kw = 0; kw < 11; ++kw) {
        const char* ap = w1tb + kw * 3072 + l31 * 96 + lhi * 16;
        const bf16x8 a0 = *(const bf16x8*)(ap);
        const bf16x8 a1 = *(const bf16x8*)(ap + 32);
        const bf16x8 a2 = *(const bf16x8*)(ap + 64);
        const int c = 2 * i + kw;
        const char* cb = lds + c * 128;
        const int sw = (c >> 1) & 7;
        const bf16x8 b00 = *(const bf16x8*)(cb + (((0 + lhi) ^ sw) << 4));
        const bf16x8 b01 = *(const bf16x8*)(cb + (((2 + lhi) ^ sw) << 4));
        const bf16x8 b02 = *(const bf16x8*)(cb + (((4 + lhi) ^ sw) << 4));
        const bf16x8 b10 = *(const bf16x8*)(cb + (((1 + lhi) ^ sw) << 4));
        const bf16x8 b11 = *(const bf16x8*)(cb + (((3 + lhi) ^ sw) << 4));
        const bf16x8 b12 = *(const bf16x8*)(cb + (((5 + lhi) ^ sw) << 4));
        acc0 = __builtin_amdgcn_mfma_f32_32x32x16_bf16(a0, b00, acc0, 0, 0, 0);
        acc0 = __builtin_amdgcn_mfma_f32_32x32x16_bf16(a1, b01, acc0, 0, 0, 0);
        acc0 = __builtin_amdgcn_mfma_f32_32x32x16_bf16(a2, b02, acc0, 0, 0, 0);
        acc1 = __builtin_amdgcn_mfma_f32_32x32x16_bf16(a0, b10, acc1, 0, 0, 0);
        acc1 = __builtin_amdgcn_mfma_f32_32x32x16_bf16(a1, b11, acc1, 0, 0, 0);
        acc1 = __builtin_amdgcn_mfma_f32_32x32x16_bf16(a2, b12, acc1, 0, 0, 0);
    }

    // ---- epilogue: bn1+clip+mask -> LDS transpose (planar) -> h1s ----
    __syncthreads();                     // x-tile reads done; reuse LDS
    const int ow  = bx * 128 + i;
    const bool vmask = ow < len;
    #pragma unroll
    for (int d1 = 0; d1 < 2; ++d1) {
        const int oh = oh0 + 4 * d1;
        if (oh <= 80) {
            #pragma unroll
            for (int q = 0; q < 4; ++q) {   // q = icq plane (oc>>3)
                float vv[4];
                #pragma unroll
                for (int rr = 0; rr < 4; ++rr) {
                    const int reg = (q << 2) + rr;
                    const int oc  = rr + (q << 3) + (lhi << 2);
                    const float s = g1[oc] * rsqrtf(v1[oc] + 1e-5f);
                    float val = ((d1 ? acc1[reg] : acc0[reg]) + b1[oc] - m1[oc]) * s + be1[oc];
                    val = fminf(fmaxf(val, 0.f), 20.f);
                    vv[rr] = vmask ? val : 0.f;
                }
                uint2 pk;
                pk.x = (unsigned int)f2bf(vv[0]) | ((unsigned int)f2bf(vv[1]) << 16);
                pk.y = (unsigned int)f2bf(vv[2]) | ((unsigned int)f2bf(vv[3]) << 16);
                *(uint2*)(lds + (((d1 << 2) + q) << 11) + i * 16 + lhi * 8) = pk;
            }
        }
    }
    __syncthreads();
    #pragma unroll
    for (int it = 0; it < 4; ++it) {
        const int idx = t + it * 256;    // 0..1023
        const int d1 = idx >> 9;
        const int q  = (idx >> 7) & 3;
        const int cl = idx & 127;
        const int oh = oh0 + 4 * d1;
        if (oh <= 80) {
            const uint4 v = *(const uint4*)(lds + (((d1 << 2) + q) << 11) + cl * 16);
            *(uint4*)(h8 + (size_t)(n * 81 + oh) * rowpitch + q * 8704
                      + (16 + (bx << 7) + cl) * 16) = v;
        }
    }
}

// ---------------------------------------------------------------------------
// conv2_v11: = v10 with the tail bug fixed. 2-wave blocks (wave = K-half s),
// tile 64 cols x 2 oh2.  LDS ring = 3 x 6144 B = 18 KB.  A sliding window:
// j1(r) == j0(r-2) -> 3-slot register window, 11 A loads/row pre-barrier.
// Main loop in exact triples + explicit 0-2 iter tail (NO padded iterations
// -- clamped-rhi groups by=18/20 hit nonzero kh weights when padded: that
// was v10's absmax-2.69 bug).  grid 2688 (16n x 21by x 8bx), scramble x1181.
// ---------------------------------------------------------------------------
__global__ __launch_bounds__(128, 2) void conv2_v11(
    const unsigned short* __restrict__ h1s, const unsigned short* __restrict__ w2tf,
    const int* __restrict__ xlen,
    const float* __restrict__ b2, const float* __restrict__ g2,
    const float* __restrict__ be2, const float* __restrict__ m2,
    const float* __restrict__ v2, float* __restrict__ out)
{
    __shared__ char ring[3 * 6144];      // 18432 B

    const int t   = threadIdx.x;
    const int w   = t >> 6;              // wave = K-half s
    const int l   = t & 63;
    const int l31 = l & 31;
    const int lhi = l >> 5;

    const int bid = blockIdx.x;
    const int lb  = (bid * 1181) % 2688; // gcd(1181, 2688) = 1
    const int n   = lb / 168;
    const int rem = lb - n * 168;
    const int by  = rem >> 3;            // 0..20: oh2 pair {2by, 2by+1}
    const int bx  = rem & 7;

    const int ow0 = bx << 6;
    const int len = xlen[n];
    const int by4 = by << 2;

    if (ow0 >= len) {                    // fully masked col-tile: zeros only
        const int oh2 = 2 * by + w;
        if (oh2 <= 40) {
            #pragma unroll
            for (int f = 0; f < 2; ++f) {
                const int ow = ow0 + (f << 5) + l31;
                #pragma unroll
                for (int reg = 0; reg < 16; ++reg) {
                    const int oc = (reg & 3) + ((reg >> 2) << 3) + (lhi << 2);
                    out[((size_t)(n * 32 + oc) * 41 + oh2) * 512 + ow] = 0.f;
                }
            }
        }
        return;
    }

    const int rlo = (by4 - 10 > 0) ? by4 - 10 : 0;
    const int rhi = (by4 + 12 < 80) ? by4 + 12 : 80;

    f32x16 a00 = {}, a01 = {}, a10 = {}, a11 = {};   // [j][f]

    const char* nb2 = (const char*)h1s + (size_t)(n * 81) * 34816;
    const char* w8v = (const char*)w2tf;

    // staging offsets: block stages 4 planes x 96 cols x 16B = 6144 B/row,
    // 3 GLL16 issues per wave; per-lane global src, linear LDS dest.
    int gso[3], lso[3];
    #pragma unroll
    for (int i = 0; i < 3; ++i) {
        const int idx = w * 192 + i * 64 + l;        // 0..383
        const int q   = idx / 96;
        const int c   = idx - q * 96;
        gso[i] = q * 8704 + (ow0 + 11 + c) * 16;
        lso[i] = idx * 16;
    }

    #define STAGE(r, buf) do { \
        const char* g_ = nb2 + (size_t)(r) * 34816; \
        char* d_ = ring + (buf) * 6144; \
        GLL16(g_ + gso[0], d_ + lso[0]); \
        GLL16(g_ + gso[1], d_ + lso[1]); \
        GLL16(g_ + gso[2], d_ + lso[2]); \
    } while (0)

    #define LOADB(S, ibv) do { \
        _Pragma("unroll") \
        for (int kw = 0; kw < 11; ++kw) \
            S[kw] = *(const bf16x8*)(w8v \
                + (size_t)((((ibv) * 11 + kw) * 2 + w) << 10) + (l << 4)); \
    } while (0)

    #define MFMAS(AJ0, AJ1, bufi) do { \
        const char* lb8_ = ring + (bufi) * 6144 + ((2 * w + lhi) * 96) * 16; \
        _Pragma("unroll") \
        for (int kw = 0; kw < 11; ++kw) { \
            const bf16x8 B0 = *(const bf16x8*)(lb8_ + (l31 + kw) * 16); \
            const bf16x8 B1 = *(const bf16x8*)(lb8_ + (l31 + kw + 32) * 16); \
            a00 = __builtin_amdgcn_mfma_f32_32x32x16_bf16(AJ0[kw], B0, a00, 0, 0, 0); \
            a01 = __builtin_amdgcn_mfma_f32_32x32x16_bf16(AJ0[kw], B1, a01, 0, 0, 0); \
            a10 = __builtin_amdgcn_mfma_f32_32x32x16_bf16(AJ1[kw], B0, a10, 0, 0, 0); \
            a11 = __builtin_amdgcn_mfma_f32_32x32x16_bf16(AJ1[kw], B1, a11, 0, 0, 0); \
        } \
    } while (0)

    #define ITER(kk, SC, SP, stbuf, rdbuf) do { \
        const int r_ = rlo + (kk); \
        LOADB(SC, r_ - by4 + 14); \
        __builtin_amdgcn_sched_barrier(0); \
        __builtin_amdgcn_s_barrier(); \
        __builtin_amdgcn_sched_barrier(0); \
        { const int rs_ = (r_ + 2 <= rhi) ? (r_ + 2) : rhi; STAGE(rs_, stbuf); } \
        MFMAS(SC, SP, rdbuf); \
    } while (0)

    bf16x8 S0[11], S1[11], S2[11];
    // prologue: j1 window (burst(rlo-2) -> S1, burst(rlo-1) -> S2), rows 0,1
    LOADB(S1, rlo - by4 + 12);
    LOADB(S2, rlo - by4 + 13);
    STAGE(rlo,     0);
    STAGE(rlo + 1, 1);
    __syncthreads();

    const int trips = rhi - rlo + 1;                 // 11..23
    int k = 0;
    for (; k + 3 <= trips; k += 3) {
        ITER(k,     S0, S1, 2, 0);
        ITER(k + 1, S1, S2, 0, 1);
        ITER(k + 2, S2, S0, 1, 2);
    }
    // exact tail (k % 3 == 0 on exit; conditions uniform in by)
    if (k < trips)     { ITER(k,     S0, S1, 2, 0); }
    if (k + 1 < trips) { ITER(k + 1, S1, S2, 0, 1); }
    #undef ITER
    #undef MFMAS
    #undef LOADB
    #undef STAGE

    // ---- cross-wave s-reduction via LDS (16 KB in ring) ----
    __syncthreads();
    if (w == 1) {
        #define WRPART(ACC, fi) do { \
            char* dst_ = ring + (fi) * 4096 + l * 64; \
            _Pragma("unroll") \
            for (int q = 0; q < 4; ++q) { \
                float4 v_; \
                v_.x = ACC[4*q]; v_.y = ACC[4*q+1]; v_.z = ACC[4*q+2]; v_.w = ACC[4*q+3]; \
                *(float4*)(dst_ + q * 16) = v_; \
            } \
        } while (0)
        WRPART(a00, 0); WRPART(a01, 1); WRPART(a10, 2); WRPART(a11, 3);
        #undef WRPART
    }
    __syncthreads();
    if (w == 1) return;

    // ---- epilogue (wave 0): add partner acc, bn2 + clip + mask -> out ----
    #define STOUT(ACC, fi, jv, fv) do { \
        const int oh2_ = 2 * by + (jv); \
        if (oh2_ <= 40) { \
            const char* src_ = ring + (fi) * 4096 + l * 64; \
            float pr_[16]; \
            _Pragma("unroll") \
            for (int q = 0; q < 4; ++q) { \
                const float4 v_ = *(const float4*)(src_ + q * 16); \
                pr_[4*q] = v_.x; pr_[4*q+1] = v_.y; pr_[4*q+2] = v_.z; pr_[4*q+3] = v_.w; \
            } \
            const int ow_ = ow0 + ((fv) << 5) + l31; \
            const bool valid_ = ow_ < len; \
            _Pragma("unroll") \
            for (int reg = 0; reg < 16; ++reg) { \
                const int oc_ = (reg & 3) + ((reg >> 2) << 3) + (lhi << 2); \
                const float sc_ = g2[oc_] * rsqrtf(v2[oc_] + 1e-5f); \
                float val_ = (ACC[reg] + pr_[reg] + b2[oc_] - m2[oc_]) * sc_ + be2[oc_]; \
                val_ = fminf(fmaxf(val_, 0.f), 20.f); \
                if (!valid_) val_ = 0.f; \
                out[((size_t)(n * 32 + oc_) * 41 + oh2_) * 512 + ow_] = val_; \
            } \
        } \
    } while (0)
    STOUT(a00, 0, 0, 0); STOUT(a01, 1, 0, 1); STOUT(a10, 2, 1, 0); STOUT(a11, 3, 1, 1);
    #undef STOUT
}

extern "C" void kernel_launch(void* const* d_in, const int* in_sizes, int n_in,
                              void* d_out, int out_size, void* d_ws, size_t ws_size,
                              hipStream_t stream) {
    const float* x    = (const float*)d_in[0];
    const int*   xlen = (const int*)  d_in[1];
    const float* w1   = (const float*)d_in[2];
    const float* b1   = (const float*)d_in[3];
    const float* g1   = (const float*)d_in[4];
    const float* be1  = (const float*)d_in[5];
    const float* m1   = (const float*)d_in[6];
    const float* v1   = (const float*)d_in[7];
    const float* w2   = (const float*)d_in[8];
    const float* b2   = (const float*)d_in[9];
    const float* g2   = (const float*)d_in[10];
    const float* be2  = (const float*)d_in[11];
    const float* m2   = (const float*)d_in[12];
    const float* v2   = (const float*)d_in[13];
    float* out = (float*)d_out;

    // ws: h1s planar 544-wide [22560768 sh], w2tf [349184 sh], w1t [16896 sh]
    unsigned short* h1s  = (unsigned short*)d_ws;
    unsigned short* w2tf = h1s + 22560768;
    unsigned short* w1t  = w2tf + 349184;

    prep_w1t<<<dim3(66),   dim3(256), 0, stream>>>(w1, w1t);
    prep_w2f<<<dim3(1364), dim3(256), 0, stream>>>(w2, w2tf);
    zero_halo<<<dim3(203), dim3(256), 0, stream>>>(h1s);
    conv1_mfma<<<dim3(4, 41, 16), dim3(256), 0, stream>>>(
        x, xlen, w1t, b1, g1, be1, m1, v1, h1s);
    conv2_v11<<<dim3(2688), dim3(128), 0, stream>>>(
        h1s, w2tf, xlen, b2, g2, be2, m2, v2, out);
}

// Round 12
// 193.326 us; speedup vs baseline: 1.6471x; 1.0589x over previous
//
#include <hip/hip_runtime.h>

typedef __attribute__((ext_vector_type(8))) __bf16 bf16x8;
typedef __attribute__((ext_vector_type(16))) float f32x16;

__device__ __forceinline__ unsigned short f2bf(float f) {
    unsigned int u = __float_as_uint(f);
    unsigned int r = (u + 0x7FFFu + ((u >> 16) & 1u)) >> 16;
    return (unsigned short)r;
}

// async global->LDS, 16B per lane (m97 pattern)
#define GLL16(gp, lp) \
    __builtin_amdgcn_global_load_lds( \
        (const __attribute__((address_space(1))) unsigned int*)(gp), \
        (__attribute__((address_space(3))) unsigned int*)(lp), 16, 0, 0)

// ---------------------------------------------------------------------------
// prep_w1t: w1 [32oc][1][41kh][11kw] f32 -> w1t [kw][oc][kh pad 48] bf16.
// ---------------------------------------------------------------------------
__global__ __launch_bounds__(256) void prep_w1t(const float* __restrict__ w1,
                                                unsigned short* __restrict__ w1t)
{
    const int t = blockIdx.x * 256 + threadIdx.x;   // 66 blocks -> exactly 16896
    const int k    = t % 48;
    const int rest = t / 48;
    const int oc   = rest & 31;
    const int kw   = rest >> 5;
    unsigned short v = 0;
    if (k < 41) v = f2bf(w1[(oc * 41 + k) * 11 + kw]);
    w1t[t] = v;
}

// ---------------------------------------------------------------------------
// prep_w2f: w2 [32oc][32ic][21][11] f32 -> dense A-fragments for 32x32x16:
//   w2tf[khpp 0..30][kw 0..10][s 0..1][lane 0..63][8 bf16],  kh = khpp - 4
// (zero outside [0,20]; pad covers sliding-window prologue).
// element: oc = l&31, ic = s*16 + (l>>5)*8 + j.
// ---------------------------------------------------------------------------
__global__ __launch_bounds__(256) void prep_w2f(const float* __restrict__ w2,
                                                unsigned short* __restrict__ w2tf)
{
    const int gid = blockIdx.x * 256 + threadIdx.x;  // 1364 blocks -> 349184 exact
    const int j  = gid & 7;
    const int l  = (gid >> 3) & 63;
    const int s  = (gid >> 9) & 1;
    const int ti = gid >> 10;        // 0..340
    const int khpp = ti / 11;
    const int kw   = ti - khpp * 11;
    const int kh   = khpp - 4;
    const int oc   = l & 31;
    const int ic   = s * 16 + ((l >> 5) << 3) + j;
    unsigned short v = 0;
    if ((unsigned)kh <= 20u)
        v = f2bf(w2[((oc * 32 + ic) * 21 + kh) * 11 + kw]);
    w2tf[gid] = v;
}

// ---------------------------------------------------------------------------
// zero_halo: zero halo cols (11..15, 528..532) of planar h1s for all (n,r,q).
// h1s layout: [n][r 0..80][q 0..3][c 0..543][16B]  (plane = 8704 B,
// row pitch = 34816 B; real outputs live at shifted cols 16..527)
// ---------------------------------------------------------------------------
__global__ __launch_bounds__(256) void zero_halo(unsigned short* __restrict__ h1s)
{
    const int id = blockIdx.x * 256 + threadIdx.x;   // 203 blocks, 51840 items
    if (id >= 51840) return;
    const int k  = id % 10;
    const int qq = (id / 10) & 3;
    const int nr = id / 40;                          // 0..1295
    const int c  = (k < 5) ? 11 + k : 523 + k;       // 11..15, 528..532
    uint4 z = {0u, 0u, 0u, 0u};
    *(uint4*)((char*)h1s + ((size_t)(nr * 4 + qq) * 544 + c) * 16) = z;
}

// ---------------------------------------------------------------------------
// conv1_mfma: conv1 (41x11, s(2,2), p(20,5)) + bias + bn1 + clip + mask,
// 11 kw-taps of M=32(oc) x K=48(kh zero-pad) x N=ow GEMM on mfma_32x32x16_bf16.
// Epilogue transposes through LDS into the planar 544-wide h1s layout.
// grid (4 ow-tiles, 41 oh-groups, 16 n), block 256.  (unchanged, verified)
// ---------------------------------------------------------------------------
__global__ __launch_bounds__(256) void conv1_mfma(
    const float* __restrict__ x, const int* __restrict__ xlen,
    const unsigned short* __restrict__ w1t,
    const float* __restrict__ b1, const float* __restrict__ g1,
    const float* __restrict__ be1, const float* __restrict__ m1,
    const float* __restrict__ v1,
    unsigned short* __restrict__ h1s)
{
    __shared__ uint4 lds4[2128];            // 34048 B: x-tile, then transpose buf
    char* lds = (char*)lds4;

    const int t  = threadIdx.x;
    const int bx = blockIdx.x;
    const int yi = blockIdx.y;
    const int n  = blockIdx.z;
    const int oh0 = ((yi >> 2) << 3) + (yi & 3);   // covers oh 0..80 with +4 pair
    const int len = xlen[n];

    const int l   = t & 63;
    const int w   = t >> 6;
    const int l31 = l & 31;
    const int lhi = l >> 5;

    char* h8 = (char*)h1s;
    const size_t rowpitch = 34816;          // 4 planes x 544 x 16B

    // dead strip: all cols masked -> store zeros, skip everything
    if (bx * 128 >= len) {
        #pragma unroll
        for (int it = 0; it < 4; ++it) {
            const int idx = t + it * 256;
            const int d1 = idx >> 9;
            const int q  = (idx >> 7) & 3;
            const int cl = idx & 127;
            const int oh = oh0 + 4 * d1;
            if (oh <= 80) {
                uint4 z = {0u, 0u, 0u, 0u};
                *(uint4*)(h8 + (size_t)(n * 81 + oh) * rowpitch + q * 8704
                          + (16 + (bx << 7) + cl) * 16) = z;
            }
        }
        return;
    }

    // ---- stage x: f32 -> bf16, transposed, swizzled ----
    const int cw   = t & 63;
    const int jrow = t >> 6;
    const int gr0  = 2 * oh0 - 20;
    const int gc0  = bx * 256 - 5;
    const float* xn = x + (size_t)n * 161 * 1024;
    #pragma unroll
    for (int cg = 0; cg < 5; ++cg) {
        const int c = cg * 64 + cw;
        if (c < 266) {
            const int gc = gc0 + c;
            const bool cok = (gc >= 0) && (gc < 1024);
            #pragma unroll
            for (int jj = 0; jj < 2; ++jj) {
                const int j = jrow + 4 * jj;       // chunk 0..6
                if (j < 7) {
                    unsigned int u[4];
                    #pragma unroll
                    for (int q = 0; q < 4; ++q) {
                        const int rA = gr0 + 8 * j + 2 * q;
                        float lo = 0.f, hi = 0.f;
                        if (cok && rA >= 0 && rA < 161)         lo = xn[(size_t)rA * 1024 + gc];
                        if (cok && rA + 1 >= 0 && rA + 1 < 161) hi = xn[(size_t)(rA + 1) * 1024 + gc];
                        u[q] = (unsigned int)f2bf(lo) | ((unsigned int)f2bf(hi) << 16);
                    }
                    uint4 val; val.x = u[0]; val.y = u[1]; val.z = u[2]; val.w = u[3];
                    *(uint4*)(lds + c * 128 + ((j ^ ((c >> 1) & 7)) << 4)) = val;
                }
            }
        }
    }
    __syncthreads();

    // ---- compute ----
    const int i = (w << 5) + l31;        // 0..127: ow within tile

    f32x16 acc0 = {}, acc1 = {};
    const char* w1tb = (const char*)w1t;
    #pragma unroll
    for (int kw = 0; kw < 11; ++kw) {
        const char* ap = w1tb + kw * 3072 + l31 * 96 + lhi * 16;
        const bf16x8 a0 = *(const bf16x8*)(ap);
        const bf16x8 a1 = *(const bf16x8*)(ap + 32);
        const bf16x8 a2 = *(const bf16x8*)(ap + 64);
        const int c = 2 * i + kw;
        const char* cb = lds + c * 128;
        const int sw = (c >> 1) & 7;
        const bf16x8 b00 = *(const bf16x8*)(cb + (((0 + lhi) ^ sw) << 4));
        const bf16x8 b01 = *(const bf16x8*)(cb + (((2 + lhi) ^ sw) << 4));
        const bf16x8 b02 = *(const bf16x8*)(cb + (((4 + lhi) ^ sw) << 4));
        const bf16x8 b10 = *(const bf16x8*)(cb + (((1 + lhi) ^ sw) << 4));
        const bf16x8 b11 = *(const bf16x8*)(cb + (((3 + lhi) ^ sw) << 4));
        const bf16x8 b12 = *(const bf16x8*)(cb + (((5 + lhi) ^ sw) << 4));
        acc0 = __builtin_amdgcn_mfma_f32_32x32x16_bf16(a0, b00, acc0, 0, 0, 0);
        acc0 = __builtin_amdgcn_mfma_f32_32x32x16_bf16(a1, b01, acc0, 0, 0, 0);
        acc0 = __builtin_amdgcn_mfma_f32_32x32x16_bf16(a2, b02, acc0, 0, 0, 0);
        acc1 = __builtin_amdgcn_mfma_f32_32x32x16_bf16(a0, b10, acc1, 0, 0, 0);
        acc1 = __builtin_amdgcn_mfma_f32_32x32x16_bf16(a1, b11, acc1, 0, 0, 0);
        acc1 = __builtin_amdgcn_mfma_f32_32x32x16_bf16(a2, b12, acc1, 0, 0, 0);
    }

    // ---- epilogue: bn1+clip+mask -> LDS transpose (planar) -> h1s ----
    __syncthreads();                     // x-tile reads done; reuse LDS
    const int ow  = bx * 128 + i;
    const bool vmask = ow < len;
    #pragma unroll
    for (int d1 = 0; d1 < 2; ++d1) {
        const int oh = oh0 + 4 * d1;
        if (oh <= 80) {
            #pragma unroll
            for (int q = 0; q < 4; ++q) {   // q = icq plane (oc>>3)
                float vv[4];
                #pragma unroll
                for (int rr = 0; rr < 4; ++rr) {
                    const int reg = (q << 2) + rr;
                    const int oc  = rr + (q << 3) + (lhi << 2);
                    const float s = g1[oc] * rsqrtf(v1[oc] + 1e-5f);
                    float val = ((d1 ? acc1[reg] : acc0[reg]) + b1[oc] - m1[oc]) * s + be1[oc];
                    val = fminf(fmaxf(val, 0.f), 20.f);
                    vv[rr] = vmask ? val : 0.f;
                }
                uint2 pk;
                pk.x = (unsigned int)f2bf(vv[0]) | ((unsigned int)f2bf(vv[1]) << 16);
                pk.y = (unsigned int)f2bf(vv[2]) | ((unsigned int)f2bf(vv[3]) << 16);
                *(uint2*)(lds + (((d1 << 2) + q) << 11) + i * 16 + lhi * 8) = pk;
            }
        }
    }
    __syncthreads();
    #pragma unroll
    for (int it = 0; it < 4; ++it) {
        const int idx = t + it * 256;    // 0..1023
        const int d1 = idx >> 9;
        const int q  = (idx >> 7) & 3;
        const int cl = idx & 127;
        const int oh = oh0 + 4 * d1;
        if (oh <= 80) {
            const uint4 v = *(const uint4*)(lds + (((d1 << 2) + q) << 11) + cl * 16);
            *(uint4*)(h8 + (size_t)(n * 81 + oh) * rowpitch + q * 8704
                      + (16 + (bx << 7) + cl) * 16) = v;
        }
    }
}

// ---------------------------------------------------------------------------
// conv2_v12: = v11 with (a) XCD-n-affinity decode (each XCD owns exactly 2 n
// -> h1s staging L2-resident; dead blocks auto-balanced per XCD) and
// (b) NO per-iteration s_barrier: the two waves touch disjoint LDS regions
// (each stages and reads exactly its own idx range), so they free-run.
// LDS-DMA ordering is enforced per-wave by explicit s_waitcnt vmcnt(3)
// (keeps only STAGE(r+2) in flight) + sched_barrier(0) (rule-18 fence).
// Reduction's __syncthreads drains outstanding DMAs before LDS reuse.
// ---------------------------------------------------------------------------
__global__ __launch_bounds__(128, 2) void conv2_v12(
    const unsigned short* __restrict__ h1s, const unsigned short* __restrict__ w2tf,
    const int* __restrict__ xlen,
    const float* __restrict__ b2, const float* __restrict__ g2,
    const float* __restrict__ be2, const float* __restrict__ m2,
    const float* __restrict__ v2, float* __restrict__ out)
{
    __shared__ char ring[3 * 6144];      // 18432 B

    const int t   = threadIdx.x;
    const int w   = t >> 6;              // wave = K-half s
    const int l   = t & 63;
    const int l31 = l & 31;
    const int lhi = l >> 5;

    // XCD-chunked bijective decode: 2688 = 8 x 336; XCD k owns n = {2k, 2k+1}
    const int bid = blockIdx.x;
    const int lb  = (bid & 7) * 336 + (bid >> 3);
    const int n   = lb / 168;
    const int rem = lb - n * 168;
    const int by  = rem >> 3;            // 0..20: oh2 pair {2by, 2by+1}
    const int bx  = rem & 7;

    const int ow0 = bx << 6;
    const int len = xlen[n];
    const int by4 = by << 2;

    if (ow0 >= len) {                    // fully masked col-tile: zeros only
        const int oh2 = 2 * by + w;
        if (oh2 <= 40) {
            #pragma unroll
            for (int f = 0; f < 2; ++f) {
                const int ow = ow0 + (f << 5) + l31;
                #pragma unroll
                for (int reg = 0; reg < 16; ++reg) {
                    const int oc = (reg & 3) + ((reg >> 2) << 3) + (lhi << 2);
                    out[((size_t)(n * 32 + oc) * 41 + oh2) * 512 + ow] = 0.f;
                }
            }
        }
        return;
    }

    const int rlo = (by4 - 10 > 0) ? by4 - 10 : 0;
    const int rhi = (by4 + 12 < 80) ? by4 + 12 : 80;

    f32x16 a00 = {}, a01 = {}, a10 = {}, a11 = {};   // [j][f]

    const char* nb2 = (const char*)h1s + (size_t)(n * 81) * 34816;
    const char* w8v = (const char*)w2tf;

    // staging offsets: block stages 4 planes x 96 cols x 16B = 6144 B/row,
    // 3 GLL16 issues per wave; per-lane global src, linear LDS dest.
    // wave w covers idx [w*192, w*192+192) == exactly the region it reads.
    int gso[3], lso[3];
    #pragma unroll
    for (int i = 0; i < 3; ++i) {
        const int idx = w * 192 + i * 64 + l;        // 0..383
        const int q   = idx / 96;
        const int c   = idx - q * 96;
        gso[i] = q * 8704 + (ow0 + 11 + c) * 16;
        lso[i] = idx * 16;
    }

    #define STAGE(r, buf) do { \
        const char* g_ = nb2 + (size_t)(r) * 34816; \
        char* d_ = ring + (buf) * 6144; \
        GLL16(g_ + gso[0], d_ + lso[0]); \
        GLL16(g_ + gso[1], d_ + lso[1]); \
        GLL16(g_ + gso[2], d_ + lso[2]); \
    } while (0)

    #define LOADB(S, ibv) do { \
        _Pragma("unroll") \
        for (int kw = 0; kw < 11; ++kw) \
            S[kw] = *(const bf16x8*)(w8v \
                + (size_t)((((ibv) * 11 + kw) * 2 + w) << 10) + (l << 4)); \
    } while (0)

    #define MFMAS(AJ0, AJ1, bufi) do { \
        const char* lb8_ = ring + (bufi) * 6144 + ((2 * w + lhi) * 96) * 16; \
        _Pragma("unroll") \
        for (int kw = 0; kw < 11; ++kw) { \
            const bf16x8 B0 = *(const bf16x8*)(lb8_ + (l31 + kw) * 16); \
            const bf16x8 B1 = *(const bf16x8*)(lb8_ + (l31 + kw + 32) * 16); \
            a00 = __builtin_amdgcn_mfma_f32_32x32x16_bf16(AJ0[kw], B0, a00, 0, 0, 0); \
            a01 = __builtin_amdgcn_mfma_f32_32x32x16_bf16(AJ0[kw], B1, a01, 0, 0, 0); \
            a10 = __builtin_amdgcn_mfma_f32_32x32x16_bf16(AJ1[kw], B0, a10, 0, 0, 0); \
            a11 = __builtin_amdgcn_mfma_f32_32x32x16_bf16(AJ1[kw], B1, a11, 0, 0, 0); \
        } \
    } while (0)

    // per-iter: A-loads for row r, stage row r+2, then fence so that
    // only STAGE(r+2) (3 ops) stays in flight -> A(r), STAGE(r), STAGE(r+1)
    // are complete (in-order vmcnt); sched_barrier stops ds_read hoisting.
    #define ITER(kk, SC, SP, stbuf, rdbuf) do { \
        const int r_ = rlo + (kk); \
        LOADB(SC, r_ - by4 + 14); \
        { const int rs_ = (r_ + 2 <= rhi) ? (r_ + 2) : rhi; STAGE(rs_, stbuf); } \
        asm volatile("s_waitcnt vmcnt(3)" ::: "memory"); \
        __builtin_amdgcn_sched_barrier(0); \
        MFMAS(SC, SP, rdbuf); \
    } while (0)

    bf16x8 S0[11], S1[11], S2[11];
    // prologue: j1 window (burst(rlo-2) -> S1, burst(rlo-1) -> S2), rows 0,1
    LOADB(S1, rlo - by4 + 12);
    LOADB(S2, rlo - by4 + 13);
    STAGE(rlo,     0);
    STAGE(rlo + 1, 1);

    const int trips = rhi - rlo + 1;                 // 11..23
    int k = 0;
    for (; k + 3 <= trips; k += 3) {
        ITER(k,     S0, S1, 2, 0);
        ITER(k + 1, S1, S2, 0, 1);
        ITER(k + 2, S2, S0, 1, 2);
    }
    // exact tail (k % 3 == 0 on exit; conditions uniform per block)
    if (k < trips)     { ITER(k,     S0, S1, 2, 0); }
    if (k + 1 < trips) { ITER(k + 1, S1, S2, 0, 1); }
    #undef ITER
    #undef MFMAS
    #undef LOADB
    #undef STAGE

    // ---- cross-wave s-reduction via LDS (16 KB in ring) ----
    __syncthreads();                     // full drain (vmcnt/lgkm) + sync
    if (w == 1) {
        #define WRPART(ACC, fi) do { \
            char* dst_ = ring + (fi) * 4096 + l * 64; \
            _Pragma("unroll") \
            for (int q = 0; q < 4; ++q) { \
                float4 v_; \
                v_.x = ACC[4*q]; v_.y = ACC[4*q+1]; v_.z = ACC[4*q+2]; v_.w = ACC[4*q+3]; \
                *(float4*)(dst_ + q * 16) = v_; \
            } \
        } while (0)
        WRPART(a00, 0); WRPART(a01, 1); WRPART(a10, 2); WRPART(a11, 3);
        #undef WRPART
    }
    __syncthreads();
    if (w == 1) return;

    // ---- epilogue (wave 0): add partner acc, bn2 + clip + mask -> out ----
    #define STOUT(ACC, fi, jv, fv) do { \
        const int oh2_ = 2 * by + (jv); \
        if (oh2_ <= 40) { \
            const char* src_ = ring + (fi) * 4096 + l * 64; \
            float pr_[16]; \
            _Pragma("unroll") \
            for (int q = 0; q < 4; ++q) { \
                const float4 v_ = *(const float4*)(src_ + q * 16); \
                pr_[4*q] = v_.x; pr_[4*q+1] = v_.y; pr_[4*q+2] = v_.z; pr_[4*q+3] = v_.w; \
            } \
            const int ow_ = ow0 + ((fv) << 5) + l31; \
            const bool valid_ = ow_ < len; \
            _Pragma("unroll") \
            for (int reg = 0; reg < 16; ++reg) { \
                const int oc_ = (reg & 3) + ((reg >> 2) << 3) + (lhi << 2); \
                const float sc_ = g2[oc_] * rsqrtf(v2[oc_] + 1e-5f); \
                float val_ = (ACC[reg] + pr_[reg] + b2[oc_] - m2[oc_]) * sc_ + be2[oc_]; \
                val_ = fminf(fmaxf(val_, 0.f), 20.f); \
                if (!valid_) val_ = 0.f; \
                out[((size_t)(n * 32 + oc_) * 41 + oh2_) * 512 + ow_] = val_; \
            } \
        } \
    } while (0)
    STOUT(a00, 0, 0, 0); STOUT(a01, 1, 0, 1); STOUT(a10, 2, 1, 0); STOUT(a11, 3, 1, 1);
    #undef STOUT
}

extern "C" void kernel_launch(void* const* d_in, const int* in_sizes, int n_in,
                              void* d_out, int out_size, void* d_ws, size_t ws_size,
                              hipStream_t stream) {
    const float* x    = (const float*)d_in[0];
    const int*   xlen = (const int*)  d_in[1];
    const float* w1   = (const float*)d_in[2];
    const float* b1   = (const float*)d_in[3];
    const float* g1   = (const float*)d_in[4];
    const float* be1  = (const float*)d_in[5];
    const float* m1   = (const float*)d_in[6];
    const float* v1   = (const float*)d_in[7];
    const float* w2   = (const float*)d_in[8];
    const float* b2   = (const float*)d_in[9];
    const float* g2   = (const float*)d_in[10];
    const float* be2  = (const float*)d_in[11];
    const float* m2   = (const float*)d_in[12];
    const float* v2   = (const float*)d_in[13];
    float* out = (float*)d_out;

    // ws: h1s planar 544-wide [22560768 sh], w2tf [349184 sh], w1t [16896 sh]
    unsigned short* h1s  = (unsigned short*)d_ws;
    unsigned short* w2tf = h1s + 22560768;
    unsigned short* w1t  = w2tf + 349184;

    prep_w1t<<<dim3(66),   dim3(256), 0, stream>>>(w1, w1t);
    prep_w2f<<<dim3(1364), dim3(256), 0, stream>>>(w2, w2tf);
    zero_halo<<<dim3(203), dim3(256), 0, stream>>>(h1s);
    conv1_mfma<<<dim3(4, 41, 16), dim3(256), 0, stream>>>(
        x, xlen, w1t, b1, g1, be1, m1, v1, h1s);
    conv2_v12<<<dim3(2688), dim3(128), 0, stream>>>(
        h1s, w2tf, xlen, b2, g2, be2, m2, v2, out);
}